// Round 3
// baseline (509.789 us; speedup 1.0000x reference)
//
#include <hip/hip_runtime.h>
#include <stdint.h>

#define FEAT 128

typedef short bf16x8 __attribute__((ext_vector_type(8)));
typedef float f32x4 __attribute__((ext_vector_type(4)));

__device__ __forceinline__ float bfs(unsigned short u) {
    uint32_t t = ((uint32_t)u) << 16;
    return __builtin_bit_cast(float, t);
}
__device__ __forceinline__ unsigned short f2bf(float f) {
    uint32_t u = __builtin_bit_cast(uint32_t, f);
    u += 0x7fffu + ((u >> 16) & 1u);
    return (unsigned short)(u >> 16);
}

// ---- dtype detection ----------------------------------------------------
// bf16-packed words: bits 14..7 of the LOW half are a bf16 exponent, con-
// centrated in [0x60,0x90] for normal-ish data (~100% hit). f32 words: those
// bits are uniform mantissa bits (~19% hit). 2*cnt > samples  =>  bf16.
__global__ void k_dtype(const uint32_t* __restrict__ p, int words, int* __restrict__ cnt) {
    int t = threadIdx.x;
    int h = 0;
    for (int i = t; i < words; i += 256) {
        unsigned e = (p[i] >> 7) & 0xFFu;
        h += (e >= 0x60u && e <= 0x90u) ? 1 : 0;
    }
    atomicAdd(cnt, h);
}

// ---- edge-index layout detection (int64 vs int32) ----------------------
__global__ void k_detect(const int* __restrict__ ei, int* __restrict__ flag) {
    int t = threadIdx.x;           // 256 threads, each checks 8 odd words
    int nz = 0;
    for (int i = 0; i < 8; i++) {
        int w = 1 + 2 * (t * 8 + i);
        nz |= ei[w];
    }
    if (nz != 0) atomicOr(flag, 1);    // 1 => int32 layout, 0 => int64
}

__device__ __forceinline__ int edge_src(const int* __restrict__ ei, int e,
                                        int is32, int E, int n) {
    int v = is32 ? ei[e] : ei[2 * e];
    return ((unsigned)v < (unsigned)n) ? v : 0;
}
__device__ __forceinline__ int edge_dst(const int* __restrict__ ei, int e,
                                        int is32, int E, int n) {
    int v = is32 ? ei[E + e] : ei[2 * E + 2 * e];
    return ((unsigned)v < (unsigned)n) ? v : 0;
}

// ---- input canonicalization --------------------------------------------

// split: value -> hi bf16 + lo bf16 (lo = 0 when input already bf16)
__global__ void k_split(const void* __restrict__ in, const int* __restrict__ cnt,
                        int samples, int m,
                        unsigned short* __restrict__ hi, unsigned short* __restrict__ lo) {
    int i = blockIdx.x * 256 + threadIdx.x;
    if (i >= m) return;
    if (2 * (*cnt) > samples) {
        hi[i] = ((const unsigned short*)in)[i];
        lo[i] = 0;
    } else {
        float f = ((const float*)in)[i];
        unsigned short h = f2bf(f);
        hi[i] = h;
        lo[i] = f2bf(f - bfs(h));
    }
}

// W [128x128] -> transposed split Wt_hi/Wt_lo [nout][k]
__global__ void k_wsplit(const void* __restrict__ W, const int* __restrict__ cnt,
                         int samples,
                         unsigned short* __restrict__ Wth, unsigned short* __restrict__ Wtl) {
    int t = blockIdx.x * 256 + threadIdx.x;  // 16384
    int nn = t >> 7, k = t & 127;
    int si = k * 128 + nn;
    float f;
    if (2 * (*cnt) > samples) f = bfs(((const unsigned short*)W)[si]);
    else                      f = ((const float*)W)[si];
    unsigned short h = f2bf(f);
    Wth[nn * 128 + k] = h;
    Wtl[nn * 128 + k] = f2bf(f - bfs(h));
}

// small tensors -> f32
__global__ void k_cvtf(const void* __restrict__ in, const int* __restrict__ cnt,
                       int samples, int m, float* __restrict__ out) {
    int i = blockIdx.x * 256 + threadIdx.x;
    if (i >= m) return;
    if (2 * (*cnt) > samples) out[i] = bfs(((const unsigned short*)in)[i]);
    else                      out[i] = ((const float*)in)[i];
}

// ---- CSR build ----------------------------------------------------------

__global__ void k_deg(const int* __restrict__ ei, const int* __restrict__ flag,
                      int* __restrict__ deg, int E, int n) {
    int e = blockIdx.x * 256 + threadIdx.x;
    if (e < E) atomicAdd(&deg[edge_dst(ei, e, *flag, E, n)], 1);
}

__global__ void k_dinv(const int* __restrict__ deg, float* __restrict__ dinv, int n) {
    int i = blockIdx.x * 256 + threadIdx.x;
    if (i < n) dinv[i] = rsqrtf((float)(deg[i] + 1));  // +1 self-loop
}

__global__ void k_scan(const int* __restrict__ deg, int* __restrict__ row_ptr,
                       int* __restrict__ cursor, int n) {
    __shared__ int wsum[16];
    __shared__ int tot;
    int t = threadIdx.x;
    int lane = t & 63;
    int w = t >> 6;
    int c = 0;
    for (int base = 0; base < n; base += 1024) {
        int idx = base + t;
        int v = (idx < n) ? deg[idx] : 0;
        int s = v;
        #pragma unroll
        for (int off = 1; off < 64; off <<= 1) {
            int x = __shfl_up(s, off, 64);
            if (lane >= off) s += x;
        }
        if (lane == 63) wsum[w] = s;
        __syncthreads();
        if (t == 0) {
            int acc = 0;
            #pragma unroll
            for (int i = 0; i < 16; i++) { int x = wsum[i]; wsum[i] = acc; acc += x; }
            tot = acc;
        }
        __syncthreads();
        int incl = s + wsum[w];
        if (idx < n) {
            int ex = c + incl - v;
            row_ptr[idx] = ex;
            cursor[idx]  = ex;
        }
        c += tot;
        __syncthreads();
    }
    if (t == 0) row_ptr[n] = c;
}

__global__ void k_scatter(const int* __restrict__ ei, const int* __restrict__ flag,
                          int* __restrict__ cursor, int* __restrict__ col,
                          int E, int n) {
    int e = blockIdx.x * 256 + threadIdx.x;
    if (e < E) {
        int is32 = *flag;
        int d = edge_dst(ei, e, is32, E, n);
        int s = edge_src(ei, e, is32, E, n);
        int p = atomicAdd(&cursor[d], 1);
        if ((unsigned)p < (unsigned)E) col[p] = s;
    }
}

// ---- GEMM: hs = dinv[row] * (X @ W), split-bf16 3-pass MFMA, f32 out ----

__launch_bounds__(64)
__global__ void k_gemm(const unsigned short* __restrict__ Xh,
                       const unsigned short* __restrict__ Xl,
                       const unsigned short* __restrict__ Wth,
                       const unsigned short* __restrict__ Wtl,
                       const float* __restrict__ dinv,
                       float* __restrict__ hs, int n) {
    int l = threadIdx.x;
    int quad = l >> 4;
    int m16 = l & 15;
    int r0 = blockIdx.x * 16;

    int ra = r0 + m16;
    if (ra > n - 1) ra = n - 1;
    const int4* Xvh = (const int4*)Xh;
    const int4* Xvl = (const int4*)Xl;
    bf16x8 ah[4], al[4];
    #pragma unroll
    for (int kt = 0; kt < 4; kt++) {
        ah[kt] = __builtin_bit_cast(bf16x8, Xvh[ra * 16 + kt * 4 + quad]);
        al[kt] = __builtin_bit_cast(bf16x8, Xvl[ra * 16 + kt * 4 + quad]);
    }

    float dv[4];
    #pragma unroll
    for (int reg = 0; reg < 4; reg++) {
        int row = r0 + quad * 4 + reg;
        if (row > n - 1) row = n - 1;
        dv[reg] = dinv[row];
    }

    const int4* Wvh = (const int4*)Wth;
    const int4* Wvl = (const int4*)Wtl;
    #pragma unroll
    for (int nt = 0; nt < 8; nt++) {
        f32x4 acc = {0.f, 0.f, 0.f, 0.f};
        int brow = (nt * 16 + m16) * 16;
        #pragma unroll
        for (int kt = 0; kt < 4; kt++) {
            bf16x8 bh = __builtin_bit_cast(bf16x8, Wvh[brow + kt * 4 + quad]);
            bf16x8 bl = __builtin_bit_cast(bf16x8, Wvl[brow + kt * 4 + quad]);
            acc = __builtin_amdgcn_mfma_f32_16x16x32_bf16(ah[kt], bh, acc, 0, 0, 0);
            acc = __builtin_amdgcn_mfma_f32_16x16x32_bf16(ah[kt], bl, acc, 0, 0, 0);
            acc = __builtin_amdgcn_mfma_f32_16x16x32_bf16(al[kt], bh, acc, 0, 0, 0);
        }
        #pragma unroll
        for (int reg = 0; reg < 4; reg++) {
            int row = r0 + quad * 4 + reg;
            if (row < n)
                hs[row * 128 + nt * 16 + m16] = acc[reg] * dv[reg];
        }
    }
}

// ---- Pull aggregation (f32): act = relu(dinv*(hs[d]+sum hs[s]) + b) -----
// output stored as hi/lo bf16 split (consumed by next GEMM / pooling)

__launch_bounds__(256)
__global__ void k_agg(const float2* __restrict__ hsv, const int* __restrict__ row_ptr,
                      const int* __restrict__ col, const float* __restrict__ dinv,
                      const float* __restrict__ bias,
                      uint32_t* __restrict__ outh, uint32_t* __restrict__ outl,
                      int n, int E) {
    int wave = threadIdx.x >> 6;
    int lane = threadIdx.x & 63;
    int node = blockIdx.x * 4 + wave;
    if (node >= n) return;

    float2 s = hsv[node * 64 + lane];   // self term (pre-scaled by dinv[node])
    float a0 = s.x, a1 = s.y;

    int e = row_ptr[node];
    int end = row_ptr[node + 1];
    if (e < 0) e = 0;
    if (end > E) end = E;

    for (; e + 4 <= end; e += 4) {
        unsigned s0 = (unsigned)col[e],     s1 = (unsigned)col[e + 1];
        unsigned s2 = (unsigned)col[e + 2], s3 = (unsigned)col[e + 3];
        if (s0 >= (unsigned)n) s0 = 0;
        if (s1 >= (unsigned)n) s1 = 0;
        if (s2 >= (unsigned)n) s2 = 0;
        if (s3 >= (unsigned)n) s3 = 0;
        float2 u0 = hsv[s0 * 64 + lane];
        float2 u1 = hsv[s1 * 64 + lane];
        float2 u2 = hsv[s2 * 64 + lane];
        float2 u3 = hsv[s3 * 64 + lane];
        a0 += u0.x + u1.x + u2.x + u3.x;
        a1 += u0.y + u1.y + u2.y + u3.y;
    }
    for (; e < end; ++e) {
        unsigned s0 = (unsigned)col[e];
        if (s0 >= (unsigned)n) s0 = 0;
        float2 u = hsv[s0 * 64 + lane];
        a0 += u.x;
        a1 += u.y;
    }

    float dv = dinv[node];
    float2 bu = ((const float2*)bias)[lane];
    float r0 = fmaxf(dv * a0 + bu.x, 0.f);
    float r1 = fmaxf(dv * a1 + bu.y, 0.f);

    unsigned short h0 = f2bf(r0), h1 = f2bf(r1);
    unsigned short l0 = f2bf(r0 - bfs(h0)), l1 = f2bf(r1 - bfs(h1));
    outh[node * 64 + lane] = (uint32_t)h0 | ((uint32_t)h1 << 16);
    outl[node * 64 + lane] = (uint32_t)l0 | ((uint32_t)l1 << 16);
}

// ---- Pooling + FC -------------------------------------------------------

__global__ void k_pool(const unsigned short* __restrict__ ah,
                       const unsigned short* __restrict__ al,
                       float* __restrict__ pooled, int n) {
    int c = threadIdx.x;      // 128 threads: one feature each
    int r0 = blockIdx.x * 256;
    int rend = r0 + 256;
    if (rend > n) rend = n;
    float s = 0.f;
    for (int r = r0; r < rend; ++r)
        s += bfs(ah[r * 128 + c]) + bfs(al[r * 128 + c]);
    atomicAdd(&pooled[c], s);
}

__global__ void k_final(const float* __restrict__ pooled,
                        const float* __restrict__ Wfcf,
                        const float* __restrict__ bfcf,
                        const int* __restrict__ xcnt, int xsamp,
                        void* __restrict__ out, int n) {
    int j = threadIdx.x;
    if (j >= 32) return;
    float s = 0.f;
    for (int c = 0; c < 128; ++c) s += pooled[c] * Wfcf[c * 32 + j];
    s = s * (1.0f / (float)n) + bfcf[j];
    if (2 * (*xcnt) > xsamp) ((unsigned short*)out)[j] = f2bf(s);
    else                     ((float*)out)[j] = s;
}

// ---- Launch -------------------------------------------------------------

extern "C" void kernel_launch(void* const* d_in, const int* in_sizes, int n_in,
                              void* d_out, int out_size, void* d_ws, size_t ws_size,
                              hipStream_t stream) {
    const void* x   = d_in[0];
    const int*  ei  = (const int*)d_in[1];
    const void* W1  = d_in[2];
    const void* b1  = d_in[3];
    const void* W2  = d_in[4];
    const void* b2  = d_in[5];
    const void* Wfc = d_in[6];
    const void* bfc = d_in[7];

    const int n = in_sizes[0] / FEAT;    // 50000
    const int E = in_sizes[1] / 2;       // 800000
    const int m = n * FEAT;              // 6.4M

    char* ws = (char*)d_ws;
    float*          hs      = (float*)(ws);                        // 25,600,000
    unsigned short* xh      = (unsigned short*)(ws + 25600000);    // 12,800,000 (also act_hi)
    unsigned short* xl      = (unsigned short*)(ws + 38400000);    // 12,800,000 (also act_lo)
    int*            col     = (int*)(ws + 51200000);               // 3,200,000
    int*            deg     = (int*)(ws + 54400000);               // 200,000
    int*            row_ptr = (int*)(ws + 54600000);               // 200,016
    int*            cursor  = (int*)(ws + 54800016);               // 200,000
    float*          dinv    = (float*)(ws + 55000016);             // 200,000
    unsigned short* Wth     = (unsigned short*)(ws + 55200016);    // 32,768
    unsigned short* Wtl     = (unsigned short*)(ws + 55232784);    // 32,768
    float*          b1f     = (float*)(ws + 55265552);             // 512
    float*          b2f     = (float*)(ws + 55266064);             // 512
    float*          Wfcf    = (float*)(ws + 55266576);             // 16,384
    float*          bfcf    = (float*)(ws + 55282960);             // 128
    float*          pooled  = (float*)(ws + 55283088);             // 512
    int*            eflag   = (int*)(ws + 55283600);               // 4
    int*            cnts    = (int*)(ws + 55283604);               // 20

    if (ws_size < 55283632) return;  // diagnostic: absmax==1.0156e-1 => ws too small

    hipMemsetAsync(deg, 0, (size_t)n * 4, stream);
    hipMemsetAsync(pooled, 0, 128 * 4, stream);
    hipMemsetAsync(eflag, 0, 24, stream);  // eflag + 5 cnts

    // dtype detection per float tensor
    const int SX = 2048, SW = 2048, SWFC = 1024, SBFC = 16;
    k_dtype<<<1, 256, 0, stream>>>((const uint32_t*)x,   SX,   &cnts[0]);
    k_dtype<<<1, 256, 0, stream>>>((const uint32_t*)W1,  SW,   &cnts[1]);
    k_dtype<<<1, 256, 0, stream>>>((const uint32_t*)W2,  SW,   &cnts[2]);
    k_dtype<<<1, 256, 0, stream>>>((const uint32_t*)Wfc, SWFC, &cnts[3]);
    k_dtype<<<1, 256, 0, stream>>>((const uint32_t*)bfc, SBFC, &cnts[4]);
    k_detect<<<1, 256, 0, stream>>>(ei, eflag);

    // CSR build
    k_deg<<<(E + 255) / 256, 256, 0, stream>>>(ei, eflag, deg, E, n);
    k_dinv<<<(n + 255) / 256, 256, 0, stream>>>(deg, dinv, n);
    k_scan<<<1, 1024, 0, stream>>>(deg, row_ptr, cursor, n);
    k_scatter<<<(E + 255) / 256, 256, 0, stream>>>(ei, eflag, cursor, col, E, n);

    // canonicalize small tensors
    k_cvtf<<<1, 128, 0, stream>>>(b1,  &cnts[0], SX,   128,  b1f);   // zeros: flag moot
    k_cvtf<<<1, 128, 0, stream>>>(b2,  &cnts[0], SX,   128,  b2f);
    k_cvtf<<<16, 256, 0, stream>>>(Wfc, &cnts[3], SWFC, 4096, Wfcf);
    k_cvtf<<<1, 32, 0, stream>>>(bfc, &cnts[4], SBFC, 32,   bfcf);

    // split x
    k_split<<<(m + 255) / 256, 256, 0, stream>>>(x, &cnts[0], SX, m, xh, xl);

    int gemm_grid = (n + 15) / 16;
    int agg_grid  = (n + 3) / 4;

    // layer 1
    k_wsplit<<<64, 256, 0, stream>>>(W1, &cnts[1], SW, Wth, Wtl);
    k_gemm<<<gemm_grid, 64, 0, stream>>>(xh, xl, Wth, Wtl, dinv, hs, n);
    k_agg<<<agg_grid, 256, 0, stream>>>((const float2*)hs, row_ptr, col, dinv, b1f,
                                        (uint32_t*)xh, (uint32_t*)xl, n, E);
    // layer 2 (act aliased into xh/xl)
    k_wsplit<<<64, 256, 0, stream>>>(W2, &cnts[2], SW, Wth, Wtl);
    k_gemm<<<gemm_grid, 64, 0, stream>>>(xh, xl, Wth, Wtl, dinv, hs, n);
    k_agg<<<agg_grid, 256, 0, stream>>>((const float2*)hs, row_ptr, col, dinv, b2f,
                                        (uint32_t*)xh, (uint32_t*)xl, n, E);

    // mean-pool + FC
    k_pool<<<(n + 255) / 256, 128, 0, stream>>>(xh, xl, pooled, n);
    k_final<<<1, 64, 0, stream>>>(pooled, Wfcf, bfcf, &cnts[0], SX, d_out, n);
}

// Round 4
// 433.020 us; speedup vs baseline: 1.1773x; 1.1773x over previous
//
#include <hip/hip_runtime.h>
#include <stdint.h>

#define FEAT 128

typedef short bf16x8 __attribute__((ext_vector_type(8)));
typedef float f32x4 __attribute__((ext_vector_type(4)));

__device__ __forceinline__ float bfs(unsigned short u) {
    uint32_t t = ((uint32_t)u) << 16;
    return __builtin_bit_cast(float, t);
}
__device__ __forceinline__ unsigned short f2bf(float f) {
    uint32_t u = __builtin_bit_cast(uint32_t, f);
    u += 0x7fffu + ((u >> 16) & 1u);
    return (unsigned short)(u >> 16);
}

// ---- dtype detection (one block per tensor) -----------------------------
// bf16-packed words: bits 14..7 of the LOW half are a bf16 exponent, in
// [0x60,0x90] for normal data (~100%). f32: uniform mantissa bits (~19%).
__global__ void k_dtype5(const uint32_t* p0, const uint32_t* p1, const uint32_t* p2,
                         const uint32_t* p3, const uint32_t* p4,
                         int w0, int w1, int w2, int w3, int w4,
                         int* __restrict__ cnts) {
    const uint32_t* p; int words;
    switch (blockIdx.x) {
        case 0: p = p0; words = w0; break;
        case 1: p = p1; words = w1; break;
        case 2: p = p2; words = w2; break;
        case 3: p = p3; words = w3; break;
        default: p = p4; words = w4; break;
    }
    int t = threadIdx.x;
    int h = 0;
    for (int i = t; i < words; i += 256) {
        unsigned e = (p[i] >> 7) & 0xFFu;
        h += (e >= 0x60u && e <= 0x90u) ? 1 : 0;
    }
    atomicAdd(&cnts[blockIdx.x], h);
}

// ---- edge-index layout detection (int64 vs int32) -----------------------
__global__ void k_detect(const int* __restrict__ ei, int* __restrict__ flag) {
    int t = threadIdx.x;
    int nz = 0;
    for (int i = 0; i < 8; i++) {
        int w = 1 + 2 * (t * 8 + i);
        nz |= ei[w];
    }
    if (nz != 0) atomicOr(flag, 1);    // 1 => int32 layout, 0 => int64
}

__device__ __forceinline__ int edge_src(const int* __restrict__ ei, int e,
                                        int is32, int E, int n) {
    int v = is32 ? ei[e] : ei[2 * e];
    return ((unsigned)v < (unsigned)n) ? v : 0;
}
__device__ __forceinline__ int edge_dst(const int* __restrict__ ei, int e,
                                        int is32, int E, int n) {
    int v = is32 ? ei[E + e] : ei[2 * E + 2 * e];
    return ((unsigned)v < (unsigned)n) ? v : 0;
}

// ---- input canonicalization ---------------------------------------------

__global__ void k_split(const void* __restrict__ in, const int* __restrict__ cnt,
                        int samples, int m,
                        unsigned short* __restrict__ hi, unsigned short* __restrict__ lo) {
    int i = blockIdx.x * 256 + threadIdx.x;
    if (i >= m) return;
    if (2 * (*cnt) > samples) {
        hi[i] = ((const unsigned short*)in)[i];
        lo[i] = 0;
    } else {
        float f = ((const float*)in)[i];
        unsigned short h = f2bf(f);
        hi[i] = h;
        lo[i] = f2bf(f - bfs(h));
    }
}

__global__ void k_wsplit(const void* __restrict__ W, const int* __restrict__ cnt,
                         int samples,
                         unsigned short* __restrict__ Wth, unsigned short* __restrict__ Wtl) {
    int t = blockIdx.x * 256 + threadIdx.x;  // 16384
    int nn = t >> 7, k = t & 127;
    int si = k * 128 + nn;
    float f;
    if (2 * (*cnt) > samples) f = bfs(((const unsigned short*)W)[si]);
    else                      f = ((const float*)W)[si];
    unsigned short h = f2bf(f);
    Wth[nn * 128 + k] = h;
    Wtl[nn * 128 + k] = f2bf(f - bfs(h));
}

// merged small-tensor convert: [b1|b2|Wfc|bfc] -> f32, one flag (Wfc's)
__global__ void k_prep(const void* b1, const void* b2, const void* Wfc, const void* bfc,
                       const int* __restrict__ cnt, int samples,
                       float* b1f, float* b2f, float* Wfcf, float* bfcf) {
    int i = blockIdx.x * 256 + threadIdx.x;   // 0..4383
    if (i >= 4384) return;
    int isbf = (2 * (*cnt) > samples) ? 1 : 0;
    const void* src; float* dst; int off;
    if (i < 128)       { src = b1;  dst = b1f;  off = i; }
    else if (i < 256)  { src = b2;  dst = b2f;  off = i - 128; }
    else if (i < 4352) { src = Wfc; dst = Wfcf; off = i - 256; }
    else               { src = bfc; dst = bfcf; off = i - 4352; }
    dst[off] = isbf ? bfs(((const unsigned short*)src)[off])
                    : ((const float*)src)[off];
}

// ---- CSR build ----------------------------------------------------------

__global__ void k_deg(const int* __restrict__ ei, const int* __restrict__ flag,
                      int* __restrict__ deg, int E, int n) {
    int e = blockIdx.x * 256 + threadIdx.x;
    if (e < E) atomicAdd(&deg[edge_dst(ei, e, *flag, E, n)], 1);
}

__global__ void k_dinv(const int* __restrict__ deg, float* __restrict__ dinv, int n) {
    int i = blockIdx.x * 256 + threadIdx.x;
    if (i < n) dinv[i] = rsqrtf((float)(deg[i] + 1));  // +1 self-loop
}

// 3-phase scan: block sums -> scan of block sums -> apply
__global__ void k_bsum(const int* __restrict__ deg, int* __restrict__ bsum, int n) {
    __shared__ int ws[4];
    int t = threadIdx.x, lane = t & 63, w = t >> 6;
    int idx = blockIdx.x * 256 + t;
    int v = (idx < n) ? deg[idx] : 0;
    #pragma unroll
    for (int off = 32; off > 0; off >>= 1) v += __shfl_down(v, off, 64);
    if (lane == 0) ws[w] = v;
    __syncthreads();
    if (t == 0) bsum[blockIdx.x] = ws[0] + ws[1] + ws[2] + ws[3];
}

__global__ void k_bscan(const int* __restrict__ bsum, int* __restrict__ boff,
                        int* __restrict__ row_ptr, int nb, int n) {
    __shared__ int wsum[4];
    int t = threadIdx.x, lane = t & 63, w = t >> 6;
    int v = (t < nb) ? bsum[t] : 0;
    int s = v;
    #pragma unroll
    for (int off = 1; off < 64; off <<= 1) {
        int x = __shfl_up(s, off, 64);
        if (lane >= off) s += x;
    }
    if (lane == 63) wsum[w] = s;
    __syncthreads();
    if (t == 0) {
        int acc = 0;
        #pragma unroll
        for (int i = 0; i < 4; i++) { int x = wsum[i]; wsum[i] = acc; acc += x; }
    }
    __syncthreads();
    int excl = s - v + wsum[w];
    if (t < nb) boff[t] = excl;
    if (t == nb - 1) row_ptr[n] = excl + v;
}

__global__ void k_bapply(const int* __restrict__ deg, const int* __restrict__ boff,
                         int* __restrict__ row_ptr, int* __restrict__ cursor, int n) {
    __shared__ int wsum[4];
    int t = threadIdx.x, lane = t & 63, w = t >> 6;
    int idx = blockIdx.x * 256 + t;
    int v = (idx < n) ? deg[idx] : 0;
    int s = v;
    #pragma unroll
    for (int off = 1; off < 64; off <<= 1) {
        int x = __shfl_up(s, off, 64);
        if (lane >= off) s += x;
    }
    if (lane == 63) wsum[w] = s;
    __syncthreads();
    if (t == 0) {
        int acc = 0;
        #pragma unroll
        for (int i = 0; i < 4; i++) { int x = wsum[i]; wsum[i] = acc; acc += x; }
    }
    __syncthreads();
    int ex = boff[blockIdx.x] + s - v + wsum[w];
    if (idx < n) {
        row_ptr[idx] = ex;
        cursor[idx]  = ex;
    }
}

__global__ void k_scatter(const int* __restrict__ ei, const int* __restrict__ flag,
                          int* __restrict__ cursor, int* __restrict__ col,
                          int E, int n) {
    int e = blockIdx.x * 256 + threadIdx.x;
    if (e < E) {
        int is32 = *flag;
        int d = edge_dst(ei, e, is32, E, n);
        int s = edge_src(ei, e, is32, E, n);
        int p = atomicAdd(&cursor[d], 1);
        if ((unsigned)p < (unsigned)E) col[p] = s;
    }
}

// ---- GEMM: hs = dinv[row] * (X @ W), split-bf16 3-pass MFMA, f32 out ----

__launch_bounds__(64)
__global__ void k_gemm(const unsigned short* __restrict__ Xh,
                       const unsigned short* __restrict__ Xl,
                       const unsigned short* __restrict__ Wth,
                       const unsigned short* __restrict__ Wtl,
                       const float* __restrict__ dinv,
                       float* __restrict__ hs, int n) {
    int l = threadIdx.x;
    int quad = l >> 4;
    int m16 = l & 15;
    int r0 = blockIdx.x * 16;

    int ra = r0 + m16;
    if (ra > n - 1) ra = n - 1;
    const int4* Xvh = (const int4*)Xh;
    const int4* Xvl = (const int4*)Xl;
    bf16x8 ah[4], al[4];
    #pragma unroll
    for (int kt = 0; kt < 4; kt++) {
        ah[kt] = __builtin_bit_cast(bf16x8, Xvh[ra * 16 + kt * 4 + quad]);
        al[kt] = __builtin_bit_cast(bf16x8, Xvl[ra * 16 + kt * 4 + quad]);
    }

    float dv[4];
    #pragma unroll
    for (int reg = 0; reg < 4; reg++) {
        int row = r0 + quad * 4 + reg;
        if (row > n - 1) row = n - 1;
        dv[reg] = dinv[row];
    }

    const int4* Wvh = (const int4*)Wth;
    const int4* Wvl = (const int4*)Wtl;
    #pragma unroll
    for (int nt = 0; nt < 8; nt++) {
        f32x4 acc = {0.f, 0.f, 0.f, 0.f};
        int brow = (nt * 16 + m16) * 16;
        #pragma unroll
        for (int kt = 0; kt < 4; kt++) {
            bf16x8 bh = __builtin_bit_cast(bf16x8, Wvh[brow + kt * 4 + quad]);
            bf16x8 bl = __builtin_bit_cast(bf16x8, Wvl[brow + kt * 4 + quad]);
            acc = __builtin_amdgcn_mfma_f32_16x16x32_bf16(ah[kt], bh, acc, 0, 0, 0);
            acc = __builtin_amdgcn_mfma_f32_16x16x32_bf16(ah[kt], bl, acc, 0, 0, 0);
            acc = __builtin_amdgcn_mfma_f32_16x16x32_bf16(al[kt], bh, acc, 0, 0, 0);
        }
        #pragma unroll
        for (int reg = 0; reg < 4; reg++) {
            int row = r0 + quad * 4 + reg;
            if (row < n)
                hs[row * 128 + nt * 16 + m16] = acc[reg] * dv[reg];
        }
    }
}

// ---- Pull aggregation: act = relu(dinv*(hs[d]+sum hs[s]) + b) -----------
// outh/outl non-null  -> store act as bf16 hi/lo split (layer 1)
// partial   non-null  -> block-reduce act into per-block pooled partials
//                        (layer 2: act itself is never materialized)

__launch_bounds__(256)
__global__ void k_agg(const float2* __restrict__ hsv, const int* __restrict__ row_ptr,
                      const int* __restrict__ col, const float* __restrict__ dinv,
                      const float* __restrict__ bias,
                      uint32_t* __restrict__ outh, uint32_t* __restrict__ outl,
                      float* __restrict__ partial,
                      int n, int E) {
    __shared__ float pl[4][128];
    int wave = threadIdx.x >> 6;
    int lane = threadIdx.x & 63;
    int node = blockIdx.x * 4 + wave;
    bool active = (node < n);
    int nd = active ? node : 0;

    float2 s = hsv[nd * 64 + lane];   // self term (pre-scaled by dinv[node])
    float a0 = s.x, a1 = s.y;

    int e = row_ptr[nd];
    int end = active ? row_ptr[nd + 1] : e;
    if (e < 0) e = 0;
    if (end > E) end = E;

    for (; e + 4 <= end; e += 4) {
        unsigned s0 = (unsigned)col[e],     s1 = (unsigned)col[e + 1];
        unsigned s2 = (unsigned)col[e + 2], s3 = (unsigned)col[e + 3];
        if (s0 >= (unsigned)n) s0 = 0;
        if (s1 >= (unsigned)n) s1 = 0;
        if (s2 >= (unsigned)n) s2 = 0;
        if (s3 >= (unsigned)n) s3 = 0;
        float2 u0 = hsv[s0 * 64 + lane];
        float2 u1 = hsv[s1 * 64 + lane];
        float2 u2 = hsv[s2 * 64 + lane];
        float2 u3 = hsv[s3 * 64 + lane];
        a0 += u0.x + u1.x + u2.x + u3.x;
        a1 += u0.y + u1.y + u2.y + u3.y;
    }
    for (; e < end; ++e) {
        unsigned s0 = (unsigned)col[e];
        if (s0 >= (unsigned)n) s0 = 0;
        float2 u = hsv[s0 * 64 + lane];
        a0 += u.x;
        a1 += u.y;
    }

    float dv = dinv[nd];
    float2 bu = ((const float2*)bias)[lane];
    float r0 = fmaxf(dv * a0 + bu.x, 0.f);
    float r1 = fmaxf(dv * a1 + bu.y, 0.f);
    if (!active) { r0 = 0.f; r1 = 0.f; }

    if (outh != nullptr && active) {
        unsigned short h0 = f2bf(r0), h1 = f2bf(r1);
        unsigned short l0 = f2bf(r0 - bfs(h0)), l1 = f2bf(r1 - bfs(h1));
        outh[node * 64 + lane] = (uint32_t)h0 | ((uint32_t)h1 << 16);
        outl[node * 64 + lane] = (uint32_t)l0 | ((uint32_t)l1 << 16);
    }
    if (partial != nullptr) {
        pl[wave][2 * lane]     = r0;
        pl[wave][2 * lane + 1] = r1;
        __syncthreads();
        int t = threadIdx.x;
        if (t < 128) {
            float ps = pl[0][t] + pl[1][t] + pl[2][t] + pl[3][t];
            partial[blockIdx.x * 128 + t] = ps;
        }
    }
}

// ---- pooled reduce + FC -------------------------------------------------

__global__ void k_reduce(const float* __restrict__ partial, float* __restrict__ pooled,
                         int nb) {
    int f = threadIdx.x;   // 128
    float s = 0.f;
    for (int r = blockIdx.x; r < nb; r += gridDim.x)
        s += partial[r * 128 + f];
    atomicAdd(&pooled[f], s);
}

__global__ void k_final(const float* __restrict__ pooled,
                        const float* __restrict__ Wfcf,
                        const float* __restrict__ bfcf,
                        const int* __restrict__ xcnt, int xsamp,
                        void* __restrict__ out, int n) {
    int j = threadIdx.x;
    if (j >= 32) return;
    float s = 0.f;
    for (int c = 0; c < 128; ++c) s += pooled[c] * Wfcf[c * 32 + j];
    s = s * (1.0f / (float)n) + bfcf[j];
    if (2 * (*xcnt) > xsamp) ((unsigned short*)out)[j] = f2bf(s);
    else                     ((float*)out)[j] = s;
}

// ---- Launch -------------------------------------------------------------

extern "C" void kernel_launch(void* const* d_in, const int* in_sizes, int n_in,
                              void* d_out, int out_size, void* d_ws, size_t ws_size,
                              hipStream_t stream) {
    const void* x   = d_in[0];
    const int*  ei  = (const int*)d_in[1];
    const void* W1  = d_in[2];
    const void* b1  = d_in[3];
    const void* W2  = d_in[4];
    const void* b2  = d_in[5];
    const void* Wfc = d_in[6];
    const void* bfc = d_in[7];

    const int n = in_sizes[0] / FEAT;    // 50000
    const int E = in_sizes[1] / 2;       // 800000
    const int m = n * FEAT;              // 6.4M
    const int nb256 = (n + 255) / 256;   // 196
    const int nagg  = (n + 3) / 4;       // 12500

    char* ws = (char*)d_ws;
    float*          hs      = (float*)(ws);                        // 25,600,000
    unsigned short* xh      = (unsigned short*)(ws + 25600000);    // 12,800,000 (act_hi / pool partials)
    unsigned short* xl      = (unsigned short*)(ws + 38400000);    // 12,800,000 (act_lo)
    int*            col     = (int*)(ws + 51200000);               // 3,200,000
    int*            deg     = (int*)(ws + 54400000);               // 200,000
    int*            row_ptr = (int*)(ws + 54600000);               // 200,016
    int*            cursor  = (int*)(ws + 54800016);               // 200,000
    float*          dinv    = (float*)(ws + 55000016);             // 200,000
    unsigned short* Wth     = (unsigned short*)(ws + 55200016);    // 32,768
    unsigned short* Wtl     = (unsigned short*)(ws + 55232784);    // 32,768
    float*          b1f     = (float*)(ws + 55265552);             // 512
    float*          b2f     = (float*)(ws + 55266064);             // 512
    float*          Wfcf    = (float*)(ws + 55266576);             // 16,384
    float*          bfcf    = (float*)(ws + 55282960);             // 128
    float*          pooled  = (float*)(ws + 55283088);             // 512
    int*            eflag   = (int*)(ws + 55283600);               // 4
    int*            cnts    = (int*)(ws + 55283604);               // 20
    int*            bsum    = (int*)(ws + 55283624);               // 1024 (256 ints)
    int*            boff    = (int*)(ws + 55284648);               // 1024

    if (ws_size < 55285672) return;  // diagnostic: zero output => ws too small

    hipMemsetAsync(deg, 0, (size_t)n * 4, stream);
    hipMemsetAsync(pooled, 0, 128 * 4, stream);
    hipMemsetAsync(eflag, 0, 24, stream);  // eflag + 5 cnts

    // dtype + edge-layout detection
    const int SX = 2048, SW = 2048, SWFC = 1024, SBFC = 16;
    k_dtype5<<<5, 256, 0, stream>>>((const uint32_t*)x, (const uint32_t*)W1,
                                    (const uint32_t*)W2, (const uint32_t*)Wfc,
                                    (const uint32_t*)bfc,
                                    SX, SW, SW, SWFC, SBFC, cnts);
    k_detect<<<1, 256, 0, stream>>>(ei, eflag);

    // CSR build
    k_deg<<<(E + 255) / 256, 256, 0, stream>>>(ei, eflag, deg, E, n);
    k_dinv<<<nb256, 256, 0, stream>>>(deg, dinv, n);
    k_bsum<<<nb256, 256, 0, stream>>>(deg, bsum, n);
    k_bscan<<<1, 256, 0, stream>>>(bsum, boff, row_ptr, nb256, n);
    k_bapply<<<nb256, 256, 0, stream>>>(deg, boff, row_ptr, cursor, n);
    k_scatter<<<(E + 255) / 256, 256, 0, stream>>>(ei, eflag, cursor, col, E, n);

    // canonicalize inputs
    k_prep<<<18, 256, 0, stream>>>(b1, b2, Wfc, bfc, &cnts[3], SWFC,
                                   b1f, b2f, Wfcf, bfcf);
    k_split<<<(m + 255) / 256, 256, 0, stream>>>(x, &cnts[0], SX, m, xh, xl);

    int gemm_grid = (n + 15) / 16;

    // layer 1: act -> xh/xl (split bf16)
    k_wsplit<<<64, 256, 0, stream>>>(W1, &cnts[1], SW, Wth, Wtl);
    k_gemm<<<gemm_grid, 64, 0, stream>>>(xh, xl, Wth, Wtl, dinv, hs, n);
    k_agg<<<nagg, 256, 0, stream>>>((const float2*)hs, row_ptr, col, dinv, b1f,
                                    (uint32_t*)xh, (uint32_t*)xl, nullptr, n, E);
    // layer 2: no act materialization; pooled partials into (dead) xh region
    float* partial = (float*)xh;
    k_wsplit<<<64, 256, 0, stream>>>(W2, &cnts[2], SW, Wth, Wtl);
    k_gemm<<<gemm_grid, 64, 0, stream>>>(xh, xl, Wth, Wtl, dinv, hs, n);
    k_agg<<<nagg, 256, 0, stream>>>((const float2*)hs, row_ptr, col, dinv, b2f,
                                    nullptr, nullptr, partial, n, E);

    // pooled reduce + FC
    k_reduce<<<64, 128, 0, stream>>>(partial, pooled, nagg);
    k_final<<<1, 64, 0, stream>>>(pooled, Wfcf, bfcf, &cnts[0], SX, d_out, n);
}

// Round 5
// 390.777 us; speedup vs baseline: 1.3046x; 1.1081x over previous
//
#include <hip/hip_runtime.h>
#include <stdint.h>

#define FEAT 128

typedef short bf16x8 __attribute__((ext_vector_type(8)));
typedef unsigned short u16x8 __attribute__((ext_vector_type(8)));
typedef float f32x4 __attribute__((ext_vector_type(4)));

__device__ __forceinline__ float bflo(uint32_t u) {
    uint32_t t = u << 16;
    return __builtin_bit_cast(float, t);
}
__device__ __forceinline__ float bfhi(uint32_t u) {
    uint32_t t = u & 0xffff0000u;
    return __builtin_bit_cast(float, t);
}
__device__ __forceinline__ float bfs(unsigned short u) {
    uint32_t t = ((uint32_t)u) << 16;
    return __builtin_bit_cast(float, t);
}
__device__ __forceinline__ unsigned short f2bf(float f) {
    uint32_t u = __builtin_bit_cast(uint32_t, f);
    u += 0x7fffu + ((u >> 16) & 1u);
    return (unsigned short)(u >> 16);
}

// ---- dtype detection (one block per tensor) -----------------------------
__global__ void k_dtype5(const uint32_t* p0, const uint32_t* p1, const uint32_t* p2,
                         const uint32_t* p3, const uint32_t* p4,
                         int w0, int w1, int w2, int w3, int w4,
                         int* __restrict__ cnts) {
    const uint32_t* p; int words;
    switch (blockIdx.x) {
        case 0: p = p0; words = w0; break;
        case 1: p = p1; words = w1; break;
        case 2: p = p2; words = w2; break;
        case 3: p = p3; words = w3; break;
        default: p = p4; words = w4; break;
    }
    int t = threadIdx.x;
    int h = 0;
    for (int i = t; i < words; i += 256) {
        unsigned e = (p[i] >> 7) & 0xFFu;
        h += (e >= 0x60u && e <= 0x90u) ? 1 : 0;
    }
    atomicAdd(&cnts[blockIdx.x], h);
}

// ---- edge-index layout detection (int64 vs int32) -----------------------
__global__ void k_detect(const int* __restrict__ ei, int* __restrict__ flag) {
    int t = threadIdx.x;
    int nz = 0;
    for (int i = 0; i < 8; i++) {
        int w = 1 + 2 * (t * 8 + i);
        nz |= ei[w];
    }
    if (nz != 0) atomicOr(flag, 1);    // 1 => int32 layout, 0 => int64
}

__device__ __forceinline__ int edge_src(const int* __restrict__ ei, int e,
                                        int is32, int E, int n) {
    int v = is32 ? ei[e] : ei[2 * e];
    return ((unsigned)v < (unsigned)n) ? v : 0;
}
__device__ __forceinline__ int edge_dst(const int* __restrict__ ei, int e,
                                        int is32, int E, int n) {
    int v = is32 ? ei[E + e] : ei[2 * E + 2 * e];
    return ((unsigned)v < (unsigned)n) ? v : 0;
}

// ---- input canonicalization ---------------------------------------------

// vectorized split: 8 elems/thread; value -> hi bf16 + lo bf16
__global__ void k_split(const void* __restrict__ in, const int* __restrict__ cnt,
                        int samples, int m8,
                        u16x8* __restrict__ hi, u16x8* __restrict__ lo) {
    int i = blockIdx.x * 256 + threadIdx.x;
    if (i >= m8) return;
    if (2 * (*cnt) > samples) {
        hi[i] = ((const u16x8*)in)[i];
        u16x8 z = {0,0,0,0,0,0,0,0};
        lo[i] = z;
    } else {
        const float4* f4 = (const float4*)in;
        float4 f0 = f4[2 * i], f1 = f4[2 * i + 1];
        float v[8] = {f0.x, f0.y, f0.z, f0.w, f1.x, f1.y, f1.z, f1.w};
        u16x8 h, l;
        #pragma unroll
        for (int j = 0; j < 8; j++) {
            unsigned short hh = f2bf(v[j]);
            h[j] = hh;
            l[j] = f2bf(v[j] - bfs(hh));
        }
        hi[i] = h;
        lo[i] = l;
    }
}

__global__ void k_wsplit(const void* __restrict__ W, const int* __restrict__ cnt,
                         int samples,
                         unsigned short* __restrict__ Wth, unsigned short* __restrict__ Wtl) {
    int t = blockIdx.x * 256 + threadIdx.x;  // 16384
    int nn = t >> 7, k = t & 127;
    int si = k * 128 + nn;
    float f;
    if (2 * (*cnt) > samples) f = bfs(((const unsigned short*)W)[si]);
    else                      f = ((const float*)W)[si];
    unsigned short h = f2bf(f);
    Wth[nn * 128 + k] = h;
    Wtl[nn * 128 + k] = f2bf(f - bfs(h));
}

// merged small-tensor convert: [b1|b2|Wfc|bfc] -> f32
__global__ void k_prep(const void* b1, const void* b2, const void* Wfc, const void* bfc,
                       const int* __restrict__ cnt, int samples,
                       float* b1f, float* b2f, float* Wfcf, float* bfcf) {
    int i = blockIdx.x * 256 + threadIdx.x;   // 0..4383
    if (i >= 4384) return;
    int isbf = (2 * (*cnt) > samples) ? 1 : 0;
    const void* src; float* dst; int off;
    if (i < 128)       { src = b1;  dst = b1f;  off = i; }
    else if (i < 256)  { src = b2;  dst = b2f;  off = i - 128; }
    else if (i < 4352) { src = Wfc; dst = Wfcf; off = i - 256; }
    else               { src = bfc; dst = bfcf; off = i - 4352; }
    dst[off] = isbf ? bfs(((const unsigned short*)src)[off])
                    : ((const float*)src)[off];
}

// ---- CSR build ----------------------------------------------------------

__global__ void k_deg(const int* __restrict__ ei, const int* __restrict__ flag,
                      int* __restrict__ deg, int E, int n) {
    int e = blockIdx.x * 256 + threadIdx.x;
    if (e < E) atomicAdd(&deg[edge_dst(ei, e, *flag, E, n)], 1);
}

// block sums (+ fused dinv)
__global__ void k_bsum(const int* __restrict__ deg, int* __restrict__ bsum,
                       float* __restrict__ dinv, int n) {
    __shared__ int ws[4];
    int t = threadIdx.x, lane = t & 63, w = t >> 6;
    int idx = blockIdx.x * 256 + t;
    int v = (idx < n) ? deg[idx] : 0;
    if (idx < n) dinv[idx] = rsqrtf((float)(v + 1));  // +1 self-loop
    int r = v;
    #pragma unroll
    for (int off = 32; off > 0; off >>= 1) r += __shfl_down(r, off, 64);
    if (lane == 0) ws[w] = r;
    __syncthreads();
    if (t == 0) bsum[blockIdx.x] = ws[0] + ws[1] + ws[2] + ws[3];
}

__global__ void k_bscan(const int* __restrict__ bsum, int* __restrict__ boff,
                        int* __restrict__ row_ptr, int nb, int n) {
    __shared__ int wsum[4];
    int t = threadIdx.x, lane = t & 63, w = t >> 6;
    int v = (t < nb) ? bsum[t] : 0;
    int s = v;
    #pragma unroll
    for (int off = 1; off < 64; off <<= 1) {
        int x = __shfl_up(s, off, 64);
        if (lane >= off) s += x;
    }
    if (lane == 63) wsum[w] = s;
    __syncthreads();
    if (t == 0) {
        int acc = 0;
        #pragma unroll
        for (int i = 0; i < 4; i++) { int x = wsum[i]; wsum[i] = acc; acc += x; }
    }
    __syncthreads();
    int excl = s - v + wsum[w];
    if (t < nb) boff[t] = excl;
    if (t == nb - 1) row_ptr[n] = excl + v;
}

__global__ void k_bapply(const int* __restrict__ deg, const int* __restrict__ boff,
                         int* __restrict__ row_ptr, int* __restrict__ cursor, int n) {
    __shared__ int wsum[4];
    int t = threadIdx.x, lane = t & 63, w = t >> 6;
    int idx = blockIdx.x * 256 + t;
    int v = (idx < n) ? deg[idx] : 0;
    int s = v;
    #pragma unroll
    for (int off = 1; off < 64; off <<= 1) {
        int x = __shfl_up(s, off, 64);
        if (lane >= off) s += x;
    }
    if (lane == 63) wsum[w] = s;
    __syncthreads();
    if (t == 0) {
        int acc = 0;
        #pragma unroll
        for (int i = 0; i < 4; i++) { int x = wsum[i]; wsum[i] = acc; acc += x; }
    }
    __syncthreads();
    int ex = boff[blockIdx.x] + s - v + wsum[w];
    if (idx < n) {
        row_ptr[idx] = ex;
        cursor[idx]  = ex;
    }
}

__global__ void k_scatter(const int* __restrict__ ei, const int* __restrict__ flag,
                          int* __restrict__ cursor, int* __restrict__ col,
                          int E, int n) {
    int e = blockIdx.x * 256 + threadIdx.x;
    if (e < E) {
        int is32 = *flag;
        int d = edge_dst(ei, e, is32, E, n);
        int s = edge_src(ei, e, is32, E, n);
        int p = atomicAdd(&cursor[d], 1);
        if ((unsigned)p < (unsigned)E) col[p] = s;
    }
}

// ---- GEMM: hs_bf16 = dinv[row] * (X @ W), split-bf16 MFMA, bf16 out -----
// use_xlo: 3-pass (x split) vs 2-pass (act1 plain bf16, W still split)

__launch_bounds__(64)
__global__ void k_gemm(const unsigned short* __restrict__ Xh,
                       const unsigned short* __restrict__ Xl,
                       const unsigned short* __restrict__ Wth,
                       const unsigned short* __restrict__ Wtl,
                       const float* __restrict__ dinv,
                       unsigned short* __restrict__ hs, int n, int use_xlo) {
    int l = threadIdx.x;
    int quad = l >> 4;
    int m16 = l & 15;
    int r0 = blockIdx.x * 16;

    int ra = r0 + m16;
    if (ra > n - 1) ra = n - 1;
    const int4* Xvh = (const int4*)Xh;
    const int4* Xvl = (const int4*)Xl;
    bf16x8 ah[4], al[4];
    #pragma unroll
    for (int kt = 0; kt < 4; kt++)
        ah[kt] = __builtin_bit_cast(bf16x8, Xvh[ra * 16 + kt * 4 + quad]);
    if (use_xlo) {
        #pragma unroll
        for (int kt = 0; kt < 4; kt++)
            al[kt] = __builtin_bit_cast(bf16x8, Xvl[ra * 16 + kt * 4 + quad]);
    }

    float dv[4];
    #pragma unroll
    for (int reg = 0; reg < 4; reg++) {
        int row = r0 + quad * 4 + reg;
        if (row > n - 1) row = n - 1;
        dv[reg] = dinv[row];
    }

    const int4* Wvh = (const int4*)Wth;
    const int4* Wvl = (const int4*)Wtl;
    #pragma unroll
    for (int nt = 0; nt < 8; nt++) {
        f32x4 acc = {0.f, 0.f, 0.f, 0.f};
        int brow = (nt * 16 + m16) * 16;
        #pragma unroll
        for (int kt = 0; kt < 4; kt++) {
            bf16x8 bh = __builtin_bit_cast(bf16x8, Wvh[brow + kt * 4 + quad]);
            bf16x8 bl = __builtin_bit_cast(bf16x8, Wvl[brow + kt * 4 + quad]);
            acc = __builtin_amdgcn_mfma_f32_16x16x32_bf16(ah[kt], bh, acc, 0, 0, 0);
            acc = __builtin_amdgcn_mfma_f32_16x16x32_bf16(ah[kt], bl, acc, 0, 0, 0);
            if (use_xlo)
                acc = __builtin_amdgcn_mfma_f32_16x16x32_bf16(al[kt], bh, acc, 0, 0, 0);
        }
        #pragma unroll
        for (int reg = 0; reg < 4; reg++) {
            int row = r0 + quad * 4 + reg;
            if (row < n)
                hs[row * 128 + nt * 16 + m16] = f2bf(acc[reg] * dv[reg]);
        }
    }
}

// ---- Pull aggregation: act = relu(dinv*(hs[d]+sum hs[s]) + b) -----------
// hs rows are 256 B bf16: word `lane` holds cols (2*lane, 2*lane+1).
// outh non-null  -> store act as plain bf16 (layer 1)
// partial non-null -> block-reduce into pooled partials (layer 2)

__launch_bounds__(256)
__global__ void k_agg(const uint32_t* __restrict__ hsv, const int* __restrict__ row_ptr,
                      const int* __restrict__ col, const float* __restrict__ dinv,
                      const float* __restrict__ bias,
                      uint32_t* __restrict__ outh, float* __restrict__ partial,
                      int n, int E) {
    __shared__ float pl[4][128];
    int wave = threadIdx.x >> 6;
    int lane = threadIdx.x & 63;
    int node = blockIdx.x * 4 + wave;
    bool active = (node < n);
    int nd = active ? node : 0;

    uint32_t su = hsv[nd * 64 + lane];   // self term (pre-scaled by dinv[node])
    float a0 = bflo(su), a1 = bfhi(su);

    int e = row_ptr[nd];
    int end = active ? row_ptr[nd + 1] : e;
    if (e < 0) e = 0;
    if (end > E) end = E;

    for (; e + 8 <= end; e += 8) {
        unsigned s0 = (unsigned)col[e],     s1 = (unsigned)col[e + 1];
        unsigned s2 = (unsigned)col[e + 2], s3 = (unsigned)col[e + 3];
        unsigned s4 = (unsigned)col[e + 4], s5 = (unsigned)col[e + 5];
        unsigned s6 = (unsigned)col[e + 6], s7 = (unsigned)col[e + 7];
        if (s0 >= (unsigned)n) s0 = 0;
        if (s1 >= (unsigned)n) s1 = 0;
        if (s2 >= (unsigned)n) s2 = 0;
        if (s3 >= (unsigned)n) s3 = 0;
        if (s4 >= (unsigned)n) s4 = 0;
        if (s5 >= (unsigned)n) s5 = 0;
        if (s6 >= (unsigned)n) s6 = 0;
        if (s7 >= (unsigned)n) s7 = 0;
        uint32_t u0 = hsv[s0 * 64 + lane];
        uint32_t u1 = hsv[s1 * 64 + lane];
        uint32_t u2 = hsv[s2 * 64 + lane];
        uint32_t u3 = hsv[s3 * 64 + lane];
        uint32_t u4 = hsv[s4 * 64 + lane];
        uint32_t u5 = hsv[s5 * 64 + lane];
        uint32_t u6 = hsv[s6 * 64 + lane];
        uint32_t u7 = hsv[s7 * 64 + lane];
        a0 += bflo(u0) + bflo(u1) + bflo(u2) + bflo(u3)
            + bflo(u4) + bflo(u5) + bflo(u6) + bflo(u7);
        a1 += bfhi(u0) + bfhi(u1) + bfhi(u2) + bfhi(u3)
            + bfhi(u4) + bfhi(u5) + bfhi(u6) + bfhi(u7);
    }
    for (; e < end; ++e) {
        unsigned s0 = (unsigned)col[e];
        if (s0 >= (unsigned)n) s0 = 0;
        uint32_t u = hsv[s0 * 64 + lane];
        a0 += bflo(u);
        a1 += bfhi(u);
    }

    float dv = dinv[nd];
    float2 bu = ((const float2*)bias)[lane];
    float r0 = fmaxf(dv * a0 + bu.x, 0.f);
    float r1 = fmaxf(dv * a1 + bu.y, 0.f);
    if (!active) { r0 = 0.f; r1 = 0.f; }

    if (outh != nullptr && active) {
        outh[node * 64 + lane] = (uint32_t)f2bf(r0) | ((uint32_t)f2bf(r1) << 16);
    }
    if (partial != nullptr) {
        pl[wave][2 * lane]     = r0;
        pl[wave][2 * lane + 1] = r1;
        __syncthreads();
        int t = threadIdx.x;
        if (t < 128) {
            float ps = pl[0][t] + pl[1][t] + pl[2][t] + pl[3][t];
            partial[blockIdx.x * 128 + t] = ps;
        }
    }
}

// ---- pooled reduce + FC -------------------------------------------------

__global__ void k_reduce(const float* __restrict__ partial, float* __restrict__ pooled,
                         int nb) {
    int f = threadIdx.x;   // 128
    float s = 0.f;
    for (int r = blockIdx.x; r < nb; r += gridDim.x)
        s += partial[r * 128 + f];
    atomicAdd(&pooled[f], s);
}

__global__ void k_final(const float* __restrict__ pooled,
                        const float* __restrict__ Wfcf,
                        const float* __restrict__ bfcf,
                        const int* __restrict__ xcnt, int xsamp,
                        void* __restrict__ out, int n) {
    int j = threadIdx.x;
    if (j >= 32) return;
    float s = 0.f;
    for (int c = 0; c < 128; ++c) s += pooled[c] * Wfcf[c * 32 + j];
    s = s * (1.0f / (float)n) + bfcf[j];
    if (2 * (*xcnt) > xsamp) ((unsigned short*)out)[j] = f2bf(s);
    else                     ((float*)out)[j] = s;
}

// ---- Launch -------------------------------------------------------------

extern "C" void kernel_launch(void* const* d_in, const int* in_sizes, int n_in,
                              void* d_out, int out_size, void* d_ws, size_t ws_size,
                              hipStream_t stream) {
    const void* x   = d_in[0];
    const int*  ei  = (const int*)d_in[1];
    const void* W1  = d_in[2];
    const void* b1  = d_in[3];
    const void* W2  = d_in[4];
    const void* b2  = d_in[5];
    const void* Wfc = d_in[6];
    const void* bfc = d_in[7];

    const int n = in_sizes[0] / FEAT;    // 50000
    const int E = in_sizes[1] / 2;       // 800000
    const int m = n * FEAT;              // 6.4M
    const int nb256 = (n + 255) / 256;   // 196
    const int nagg  = (n + 3) / 4;       // 12500

    char* ws = (char*)d_ws;
    unsigned short* hs      = (unsigned short*)(ws);               // 12,800,000 bf16 hs
    unsigned short* xh      = (unsigned short*)(ws + 12800000);    // 12,800,000 (x hi / act1)
    unsigned short* xl      = (unsigned short*)(ws + 25600000);    // 12,800,000 (x lo / L2 partials)
    int*            col     = (int*)(ws + 38400000);               // 3,200,000
    int*            deg     = (int*)(ws + 41600000);               // 200,000
    int*            row_ptr = (int*)(ws + 41800000);               // 200,016
    int*            cursor  = (int*)(ws + 42000016);               // 200,000
    float*          dinv    = (float*)(ws + 42200016);             // 200,000
    unsigned short* Wth     = (unsigned short*)(ws + 42400016);    // 32,768
    unsigned short* Wtl     = (unsigned short*)(ws + 42432784);    // 32,768
    float*          b1f     = (float*)(ws + 42465552);             // 512
    float*          b2f     = (float*)(ws + 42466064);             // 512
    float*          Wfcf    = (float*)(ws + 42466576);             // 16,384
    float*          bfcf    = (float*)(ws + 42482960);             // 128
    float*          pooled  = (float*)(ws + 42483088);             // 512
    int*            eflag   = (int*)(ws + 42483600);               // 4
    int*            cnts    = (int*)(ws + 42483604);               // 20
    int*            bsum    = (int*)(ws + 42483624);               // 1,024
    int*            boff    = (int*)(ws + 42484648);               // 1,024

    if (ws_size < 42485672) return;  // diagnostic: zero output => ws too small

    hipMemsetAsync(deg, 0, (size_t)n * 4, stream);
    hipMemsetAsync(pooled, 0, 128 * 4, stream);
    hipMemsetAsync(eflag, 0, 24, stream);  // eflag + 5 cnts

    // dtype + edge-layout detection
    const int SX = 2048, SW = 2048, SWFC = 1024, SBFC = 16;
    k_dtype5<<<5, 256, 0, stream>>>((const uint32_t*)x, (const uint32_t*)W1,
                                    (const uint32_t*)W2, (const uint32_t*)Wfc,
                                    (const uint32_t*)bfc,
                                    SX, SW, SW, SWFC, SBFC, cnts);
    k_detect<<<1, 256, 0, stream>>>(ei, eflag);

    // CSR build
    k_deg<<<(E + 255) / 256, 256, 0, stream>>>(ei, eflag, deg, E, n);
    k_bsum<<<nb256, 256, 0, stream>>>(deg, bsum, dinv, n);
    k_bscan<<<1, 256, 0, stream>>>(bsum, boff, row_ptr, nb256, n);
    k_bapply<<<nb256, 256, 0, stream>>>(deg, boff, row_ptr, cursor, n);
    k_scatter<<<(E + 255) / 256, 256, 0, stream>>>(ei, eflag, cursor, col, E, n);

    // canonicalize inputs
    k_prep<<<18, 256, 0, stream>>>(b1, b2, Wfc, bfc, &cnts[3], SWFC,
                                   b1f, b2f, Wfcf, bfcf);
    k_split<<<(m / 8 + 255) / 256, 256, 0, stream>>>(x, &cnts[0], SX, m / 8,
                                                     (u16x8*)xh, (u16x8*)xl);

    int gemm_grid = (n + 15) / 16;

    // layer 1: act1 -> xh (plain bf16, overwrites x hi after its last use)
    k_wsplit<<<64, 256, 0, stream>>>(W1, &cnts[1], SW, Wth, Wtl);
    k_gemm<<<gemm_grid, 64, 0, stream>>>(xh, xl, Wth, Wtl, dinv, hs, n, 1);
    k_agg<<<nagg, 256, 0, stream>>>((const uint32_t*)hs, row_ptr, col, dinv, b1f,
                                    (uint32_t*)xh, nullptr, n, E);
    // layer 2: act never materialized; pooled partials into xl region
    float* partial = (float*)xl;
    k_wsplit<<<64, 256, 0, stream>>>(W2, &cnts[2], SW, Wth, Wtl);
    k_gemm<<<gemm_grid, 64, 0, stream>>>(xh, nullptr, Wth, Wtl, dinv, hs, n, 0);
    k_agg<<<nagg, 256, 0, stream>>>((const uint32_t*)hs, row_ptr, col, dinv, b2f,
                                    nullptr, partial, n, E);

    // pooled reduce + FC
    k_reduce<<<64, 128, 0, stream>>>(partial, pooled, nagg);
    k_final<<<1, 64, 0, stream>>>(pooled, Wfcf, bfcf, &cnts[0], SX, d_out, n);
}

// Round 6
// 390.046 us; speedup vs baseline: 1.3070x; 1.0019x over previous
//
#include <hip/hip_runtime.h>
#include <stdint.h>

#define FEAT 128

typedef short bf16x8 __attribute__((ext_vector_type(8)));
typedef unsigned short u16x8 __attribute__((ext_vector_type(8)));
typedef float f32x4 __attribute__((ext_vector_type(4)));

__device__ __forceinline__ float bflo(uint32_t u) {
    uint32_t t = u << 16;
    return __builtin_bit_cast(float, t);
}
__device__ __forceinline__ float bfhi(uint32_t u) {
    uint32_t t = u & 0xffff0000u;
    return __builtin_bit_cast(float, t);
}
__device__ __forceinline__ float bfs(unsigned short u) {
    uint32_t t = ((uint32_t)u) << 16;
    return __builtin_bit_cast(float, t);
}
__device__ __forceinline__ unsigned short f2bf(float f) {
    uint32_t u = __builtin_bit_cast(uint32_t, f);
    u += 0x7fffu + ((u >> 16) & 1u);
    return (unsigned short)(u >> 16);
}

// ---- dtype detection (one block per tensor) -----------------------------
__global__ void k_dtype5(const uint32_t* p0, const uint32_t* p1, const uint32_t* p2,
                         const uint32_t* p3, const uint32_t* p4,
                         int w0, int w1, int w2, int w3, int w4,
                         int* __restrict__ cnts) {
    const uint32_t* p; int words;
    switch (blockIdx.x) {
        case 0: p = p0; words = w0; break;
        case 1: p = p1; words = w1; break;
        case 2: p = p2; words = w2; break;
        case 3: p = p3; words = w3; break;
        default: p = p4; words = w4; break;
    }
    int t = threadIdx.x;
    int h = 0;
    for (int i = t; i < words; i += 256) {
        unsigned e = (p[i] >> 7) & 0xFFu;
        h += (e >= 0x60u && e <= 0x90u) ? 1 : 0;
    }
    atomicAdd(&cnts[blockIdx.x], h);
}

// ---- edge-index layout detection (int64 vs int32) -----------------------
__global__ void k_detect(const int* __restrict__ ei, int* __restrict__ flag) {
    int t = threadIdx.x;
    int nz = 0;
    for (int i = 0; i < 8; i++) {
        int w = 1 + 2 * (t * 8 + i);
        nz |= ei[w];
    }
    if (nz != 0) atomicOr(flag, 1);    // 1 => int32 layout, 0 => int64
}

// ---- edge decode: int64/int32 -> clamped int32 SoA ----------------------
__global__ void k_econv(const int* __restrict__ ei, const int* __restrict__ flag,
                        int* __restrict__ dstA, int* __restrict__ srcA,
                        int E, int n) {
    int e = blockIdx.x * 256 + threadIdx.x;
    if (e >= E) return;
    int is32 = *flag;
    int s = is32 ? ei[e]     : ei[2 * e];
    int d = is32 ? ei[E + e] : ei[2 * E + 2 * e];
    if ((unsigned)s >= (unsigned)n) s = 0;
    if ((unsigned)d >= (unsigned)n) d = 0;
    srcA[e] = s;
    dstA[e] = d;
}

// ---- input canonicalization ---------------------------------------------

__global__ void k_split(const void* __restrict__ in, const int* __restrict__ cnt,
                        int samples, int m8,
                        u16x8* __restrict__ hi, u16x8* __restrict__ lo) {
    int i = blockIdx.x * 256 + threadIdx.x;
    if (i >= m8) return;
    if (2 * (*cnt) > samples) {
        hi[i] = ((const u16x8*)in)[i];
        u16x8 z = {0,0,0,0,0,0,0,0};
        lo[i] = z;
    } else {
        const float4* f4 = (const float4*)in;
        float4 f0 = f4[2 * i], f1 = f4[2 * i + 1];
        float v[8] = {f0.x, f0.y, f0.z, f0.w, f1.x, f1.y, f1.z, f1.w};
        u16x8 h, l;
        #pragma unroll
        for (int j = 0; j < 8; j++) {
            unsigned short hh = f2bf(v[j]);
            h[j] = hh;
            l[j] = f2bf(v[j] - bfs(hh));
        }
        hi[i] = h;
        lo[i] = l;
    }
}

__global__ void k_wsplit(const void* __restrict__ W, const int* __restrict__ cnt,
                         int samples,
                         unsigned short* __restrict__ Wth, unsigned short* __restrict__ Wtl) {
    int t = blockIdx.x * 256 + threadIdx.x;  // 16384
    int nn = t >> 7, k = t & 127;
    int si = k * 128 + nn;
    float f;
    if (2 * (*cnt) > samples) f = bfs(((const unsigned short*)W)[si]);
    else                      f = ((const float*)W)[si];
    unsigned short h = f2bf(f);
    Wth[nn * 128 + k] = h;
    Wtl[nn * 128 + k] = f2bf(f - bfs(h));
}

// merged small-tensor convert: [b1|b2|Wfc|bfc] -> f32
__global__ void k_prep(const void* b1, const void* b2, const void* Wfc, const void* bfc,
                       const int* __restrict__ cnt, int samples,
                       float* b1f, float* b2f, float* Wfcf, float* bfcf) {
    int i = blockIdx.x * 256 + threadIdx.x;   // 0..4383
    if (i >= 4384) return;
    int isbf = (2 * (*cnt) > samples) ? 1 : 0;
    const void* src; float* dst; int off;
    if (i < 128)       { src = b1;  dst = b1f;  off = i; }
    else if (i < 256)  { src = b2;  dst = b2f;  off = i - 128; }
    else if (i < 4352) { src = Wfc; dst = Wfcf; off = i - 256; }
    else               { src = bfc; dst = bfcf; off = i - 4352; }
    dst[off] = isbf ? bfs(((const unsigned short*)src)[off])
                    : ((const float*)src)[off];
}

// ---- CSR build, XCD-partitioned -----------------------------------------
// grid = nchunks*8; part = blockIdx%8 (round-robin -> same XCD per part).
// Each block scans its 2048-edge chunk sequentially (L3-cached) and only
// touches deg/cursor/col for dst in its partition -> writes stay XCD-local.

__global__ void k_degp(const int* __restrict__ dstA, int* __restrict__ deg,
                       int E, int psz) {
    int part  = blockIdx.x & 7;
    int chunk = blockIdx.x >> 3;
    int base  = chunk * 2048;
    int lo = part * psz, hi = lo + psz;
    #pragma unroll
    for (int j = 0; j < 8; j++) {
        int e = base + j * 256 + threadIdx.x;
        if (e < E) {
            int d = dstA[e];
            if (d >= lo && d < hi) atomicAdd(&deg[d], 1);
        }
    }
}

__global__ void k_scatp(const int* __restrict__ dstA, const int* __restrict__ srcA,
                        int* __restrict__ cursor, int* __restrict__ col,
                        int E, int psz) {
    int part  = blockIdx.x & 7;
    int chunk = blockIdx.x >> 3;
    int base  = chunk * 2048;
    int lo = part * psz, hi = lo + psz;
    #pragma unroll
    for (int j = 0; j < 8; j++) {
        int e = base + j * 256 + threadIdx.x;
        if (e < E) {
            int d = dstA[e];
            if (d >= lo && d < hi) {
                int p = atomicAdd(&cursor[d], 1);
                if ((unsigned)p < (unsigned)E) col[p] = srcA[e];
            }
        }
    }
}

// block sums (+ fused dinv)
__global__ void k_bsum(const int* __restrict__ deg, int* __restrict__ bsum,
                       float* __restrict__ dinv, int n) {
    __shared__ int ws[4];
    int t = threadIdx.x, lane = t & 63, w = t >> 6;
    int idx = blockIdx.x * 256 + t;
    int v = (idx < n) ? deg[idx] : 0;
    if (idx < n) dinv[idx] = rsqrtf((float)(v + 1));  // +1 self-loop
    int r = v;
    #pragma unroll
    for (int off = 32; off > 0; off >>= 1) r += __shfl_down(r, off, 64);
    if (lane == 0) ws[w] = r;
    __syncthreads();
    if (t == 0) bsum[blockIdx.x] = ws[0] + ws[1] + ws[2] + ws[3];
}

__global__ void k_bscan(const int* __restrict__ bsum, int* __restrict__ boff,
                        int* __restrict__ row_ptr, int nb, int n) {
    __shared__ int wsum[4];
    int t = threadIdx.x, lane = t & 63, w = t >> 6;
    int v = (t < nb) ? bsum[t] : 0;
    int s = v;
    #pragma unroll
    for (int off = 1; off < 64; off <<= 1) {
        int x = __shfl_up(s, off, 64);
        if (lane >= off) s += x;
    }
    if (lane == 63) wsum[w] = s;
    __syncthreads();
    if (t == 0) {
        int acc = 0;
        #pragma unroll
        for (int i = 0; i < 4; i++) { int x = wsum[i]; wsum[i] = acc; acc += x; }
    }
    __syncthreads();
    int excl = s - v + wsum[w];
    if (t < nb) boff[t] = excl;
    if (t == nb - 1) row_ptr[n] = excl + v;
}

__global__ void k_bapply(const int* __restrict__ deg, const int* __restrict__ boff,
                         int* __restrict__ row_ptr, int* __restrict__ cursor, int n) {
    __shared__ int wsum[4];
    int t = threadIdx.x, lane = t & 63, w = t >> 6;
    int idx = blockIdx.x * 256 + t;
    int v = (idx < n) ? deg[idx] : 0;
    int s = v;
    #pragma unroll
    for (int off = 1; off < 64; off <<= 1) {
        int x = __shfl_up(s, off, 64);
        if (lane >= off) s += x;
    }
    if (lane == 63) wsum[w] = s;
    __syncthreads();
    if (t == 0) {
        int acc = 0;
        #pragma unroll
        for (int i = 0; i < 4; i++) { int x = wsum[i]; wsum[i] = acc; acc += x; }
    }
    __syncthreads();
    int ex = boff[blockIdx.x] + s - v + wsum[w];
    if (idx < n) {
        row_ptr[idx] = ex;
        cursor[idx]  = ex;
    }
}

// ---- GEMM: hs_bf16 = dinv[row] * (X @ W), split-bf16 MFMA, bf16 out -----

__launch_bounds__(64)
__global__ void k_gemm(const unsigned short* __restrict__ Xh,
                       const unsigned short* __restrict__ Xl,
                       const unsigned short* __restrict__ Wth,
                       const unsigned short* __restrict__ Wtl,
                       const float* __restrict__ dinv,
                       unsigned short* __restrict__ hs, int n, int use_xlo) {
    int l = threadIdx.x;
    int quad = l >> 4;
    int m16 = l & 15;
    int r0 = blockIdx.x * 16;

    int ra = r0 + m16;
    if (ra > n - 1) ra = n - 1;
    const int4* Xvh = (const int4*)Xh;
    const int4* Xvl = (const int4*)Xl;
    bf16x8 ah[4], al[4];
    #pragma unroll
    for (int kt = 0; kt < 4; kt++)
        ah[kt] = __builtin_bit_cast(bf16x8, Xvh[ra * 16 + kt * 4 + quad]);
    if (use_xlo) {
        #pragma unroll
        for (int kt = 0; kt < 4; kt++)
            al[kt] = __builtin_bit_cast(bf16x8, Xvl[ra * 16 + kt * 4 + quad]);
    }

    float dv[4];
    #pragma unroll
    for (int reg = 0; reg < 4; reg++) {
        int row = r0 + quad * 4 + reg;
        if (row > n - 1) row = n - 1;
        dv[reg] = dinv[row];
    }

    const int4* Wvh = (const int4*)Wth;
    const int4* Wvl = (const int4*)Wtl;
    #pragma unroll
    for (int nt = 0; nt < 8; nt++) {
        f32x4 acc = {0.f, 0.f, 0.f, 0.f};
        int brow = (nt * 16 + m16) * 16;
        #pragma unroll
        for (int kt = 0; kt < 4; kt++) {
            bf16x8 bh = __builtin_bit_cast(bf16x8, Wvh[brow + kt * 4 + quad]);
            bf16x8 bl = __builtin_bit_cast(bf16x8, Wvl[brow + kt * 4 + quad]);
            acc = __builtin_amdgcn_mfma_f32_16x16x32_bf16(ah[kt], bh, acc, 0, 0, 0);
            acc = __builtin_amdgcn_mfma_f32_16x16x32_bf16(ah[kt], bl, acc, 0, 0, 0);
            if (use_xlo)
                acc = __builtin_amdgcn_mfma_f32_16x16x32_bf16(al[kt], bh, acc, 0, 0, 0);
        }
        #pragma unroll
        for (int reg = 0; reg < 4; reg++) {
            int row = r0 + quad * 4 + reg;
            if (row < n)
                hs[row * 128 + nt * 16 + m16] = f2bf(acc[reg] * dv[reg]);
        }
    }
}

// ---- Pull aggregation: act = relu(dinv*(hs[d]+sum hs[s]) + b) -----------

__launch_bounds__(256)
__global__ void k_agg(const uint32_t* __restrict__ hsv, const int* __restrict__ row_ptr,
                      const int* __restrict__ col, const float* __restrict__ dinv,
                      const float* __restrict__ bias,
                      uint32_t* __restrict__ outh, float* __restrict__ partial,
                      int n, int E) {
    __shared__ float pl[4][128];
    int wave = threadIdx.x >> 6;
    int lane = threadIdx.x & 63;
    int node = blockIdx.x * 4 + wave;
    bool active = (node < n);
    int nd = active ? node : 0;

    uint32_t su = hsv[nd * 64 + lane];   // self term (pre-scaled by dinv[node])
    float a0 = bflo(su), a1 = bfhi(su);

    int e = row_ptr[nd];
    int end = active ? row_ptr[nd + 1] : e;
    if (e < 0) e = 0;
    if (end > E) end = E;

    for (; e + 8 <= end; e += 8) {
        unsigned s0 = (unsigned)col[e],     s1 = (unsigned)col[e + 1];
        unsigned s2 = (unsigned)col[e + 2], s3 = (unsigned)col[e + 3];
        unsigned s4 = (unsigned)col[e + 4], s5 = (unsigned)col[e + 5];
        unsigned s6 = (unsigned)col[e + 6], s7 = (unsigned)col[e + 7];
        if (s0 >= (unsigned)n) s0 = 0;
        if (s1 >= (unsigned)n) s1 = 0;
        if (s2 >= (unsigned)n) s2 = 0;
        if (s3 >= (unsigned)n) s3 = 0;
        if (s4 >= (unsigned)n) s4 = 0;
        if (s5 >= (unsigned)n) s5 = 0;
        if (s6 >= (unsigned)n) s6 = 0;
        if (s7 >= (unsigned)n) s7 = 0;
        uint32_t u0 = hsv[s0 * 64 + lane];
        uint32_t u1 = hsv[s1 * 64 + lane];
        uint32_t u2 = hsv[s2 * 64 + lane];
        uint32_t u3 = hsv[s3 * 64 + lane];
        uint32_t u4 = hsv[s4 * 64 + lane];
        uint32_t u5 = hsv[s5 * 64 + lane];
        uint32_t u6 = hsv[s6 * 64 + lane];
        uint32_t u7 = hsv[s7 * 64 + lane];
        a0 += bflo(u0) + bflo(u1) + bflo(u2) + bflo(u3)
            + bflo(u4) + bflo(u5) + bflo(u6) + bflo(u7);
        a1 += bfhi(u0) + bfhi(u1) + bfhi(u2) + bfhi(u3)
            + bfhi(u4) + bfhi(u5) + bfhi(u6) + bfhi(u7);
    }
    for (; e < end; ++e) {
        unsigned s0 = (unsigned)col[e];
        if (s0 >= (unsigned)n) s0 = 0;
        uint32_t u = hsv[s0 * 64 + lane];
        a0 += bflo(u);
        a1 += bfhi(u);
    }

    float dv = dinv[nd];
    float2 bu = ((const float2*)bias)[lane];
    float r0 = fmaxf(dv * a0 + bu.x, 0.f);
    float r1 = fmaxf(dv * a1 + bu.y, 0.f);
    if (!active) { r0 = 0.f; r1 = 0.f; }

    if (outh != nullptr && active) {
        outh[node * 64 + lane] = (uint32_t)f2bf(r0) | ((uint32_t)f2bf(r1) << 16);
    }
    if (partial != nullptr) {
        pl[wave][2 * lane]     = r0;
        pl[wave][2 * lane + 1] = r1;
        __syncthreads();
        int t = threadIdx.x;
        if (t < 128) {
            float ps = pl[0][t] + pl[1][t] + pl[2][t] + pl[3][t];
            partial[blockIdx.x * 128 + t] = ps;
        }
    }
}

// ---- pooled reduce + FC -------------------------------------------------

__global__ void k_reduce(const float* __restrict__ partial, float* __restrict__ pooled,
                         int nb) {
    int f = threadIdx.x;   // 128
    float s = 0.f;
    for (int r = blockIdx.x; r < nb; r += gridDim.x)
        s += partial[r * 128 + f];
    atomicAdd(&pooled[f], s);
}

__global__ void k_final(const float* __restrict__ pooled,
                        const float* __restrict__ Wfcf,
                        const float* __restrict__ bfcf,
                        const int* __restrict__ xcnt, int xsamp,
                        void* __restrict__ out, int n) {
    int j = threadIdx.x;
    if (j >= 32) return;
    float s = 0.f;
    for (int c = 0; c < 128; ++c) s += pooled[c] * Wfcf[c * 32 + j];
    s = s * (1.0f / (float)n) + bfcf[j];
    if (2 * (*xcnt) > xsamp) ((unsigned short*)out)[j] = f2bf(s);
    else                     ((float*)out)[j] = s;
}

// ---- Launch -------------------------------------------------------------

extern "C" void kernel_launch(void* const* d_in, const int* in_sizes, int n_in,
                              void* d_out, int out_size, void* d_ws, size_t ws_size,
                              hipStream_t stream) {
    const void* x   = d_in[0];
    const int*  ei  = (const int*)d_in[1];
    const void* W1  = d_in[2];
    const void* b1  = d_in[3];
    const void* W2  = d_in[4];
    const void* b2  = d_in[5];
    const void* Wfc = d_in[6];
    const void* bfc = d_in[7];

    const int n = in_sizes[0] / FEAT;    // 50000
    const int E = in_sizes[1] / 2;       // 800000
    const int m = n * FEAT;              // 6.4M
    const int nb256 = (n + 255) / 256;   // 196
    const int nagg  = (n + 3) / 4;       // 12500
    const int psz   = (n + 7) / 8;       // dst-partition size (8 XCDs)
    const int nchunks = (E + 2047) / 2048;

    char* ws = (char*)d_ws;
    unsigned short* hs      = (unsigned short*)(ws);               // 12,800,000 bf16 hs
    unsigned short* xh      = (unsigned short*)(ws + 12800000);    // 12,800,000 (x hi / act1)
    unsigned short* xl      = (unsigned short*)(ws + 25600000);    // 12,800,000 (x lo / L2 partials)
    int*            col     = (int*)(ws + 38400000);               // 3,200,000
    int*            dstA    = (int*)(ws + 41600000);               // 3,200,000
    int*            srcA    = (int*)(ws + 44800000);               // 3,200,000
    int*            deg     = (int*)(ws + 48000000);               // 200,000
    int*            row_ptr = (int*)(ws + 48200000);               // 200,016
    int*            cursor  = (int*)(ws + 48400016);               // 200,000
    float*          dinv    = (float*)(ws + 48600016);             // 200,000
    unsigned short* Wth     = (unsigned short*)(ws + 48800016);    // 32,768
    unsigned short* Wtl     = (unsigned short*)(ws + 48832784);    // 32,768
    float*          b1f     = (float*)(ws + 48865552);             // 512
    float*          b2f     = (float*)(ws + 48866064);             // 512
    float*          Wfcf    = (float*)(ws + 48866576);             // 16,384
    float*          bfcf    = (float*)(ws + 48882960);             // 128
    float*          pooled  = (float*)(ws + 48883088);             // 512
    int*            eflag   = (int*)(ws + 48883600);               // 4
    int*            cnts    = (int*)(ws + 48883604);               // 20
    int*            bsum    = (int*)(ws + 48883624);               // 1,024
    int*            boff    = (int*)(ws + 48884648);               // 1,024

    if (ws_size < 48885672) return;  // diagnostic: zero output => ws too small

    hipMemsetAsync(deg, 0, (size_t)n * 4, stream);
    hipMemsetAsync(pooled, 0, 128 * 4, stream);
    hipMemsetAsync(eflag, 0, 24, stream);  // eflag + 5 cnts

    // dtype + edge-layout detection
    const int SX = 2048, SW = 2048, SWFC = 1024, SBFC = 16;
    k_dtype5<<<5, 256, 0, stream>>>((const uint32_t*)x, (const uint32_t*)W1,
                                    (const uint32_t*)W2, (const uint32_t*)Wfc,
                                    (const uint32_t*)bfc,
                                    SX, SW, SW, SWFC, SBFC, cnts);
    k_detect<<<1, 256, 0, stream>>>(ei, eflag);

    // CSR build (XCD-partitioned deg/scatter)
    k_econv<<<(E + 255) / 256, 256, 0, stream>>>(ei, eflag, dstA, srcA, E, n);
    k_degp<<<nchunks * 8, 256, 0, stream>>>(dstA, deg, E, psz);
    k_bsum<<<nb256, 256, 0, stream>>>(deg, bsum, dinv, n);
    k_bscan<<<1, 256, 0, stream>>>(bsum, boff, row_ptr, nb256, n);
    k_bapply<<<nb256, 256, 0, stream>>>(deg, boff, row_ptr, cursor, n);
    k_scatp<<<nchunks * 8, 256, 0, stream>>>(dstA, srcA, cursor, col, E, psz);

    // canonicalize inputs
    k_prep<<<18, 256, 0, stream>>>(b1, b2, Wfc, bfc, &cnts[3], SWFC,
                                   b1f, b2f, Wfcf, bfcf);
    k_split<<<(m / 8 + 255) / 256, 256, 0, stream>>>(x, &cnts[0], SX, m / 8,
                                                     (u16x8*)xh, (u16x8*)xl);

    int gemm_grid = (n + 15) / 16;

    // layer 1: act1 -> xh (plain bf16, overwrites x hi after its last use)
    k_wsplit<<<64, 256, 0, stream>>>(W1, &cnts[1], SW, Wth, Wtl);
    k_gemm<<<gemm_grid, 64, 0, stream>>>(xh, xl, Wth, Wtl, dinv, hs, n, 1);
    k_agg<<<nagg, 256, 0, stream>>>((const uint32_t*)hs, row_ptr, col, dinv, b1f,
                                    (uint32_t*)xh, nullptr, n, E);
    // layer 2: act never materialized; pooled partials into xl region
    float* partial = (float*)xl;
    k_wsplit<<<64, 256, 0, stream>>>(W2, &cnts[2], SW, Wth, Wtl);
    k_gemm<<<gemm_grid, 64, 0, stream>>>(xh, nullptr, Wth, Wtl, dinv, hs, n, 0);
    k_agg<<<nagg, 256, 0, stream>>>((const uint32_t*)hs, row_ptr, col, dinv, b2f,
                                    nullptr, partial, n, E);

    // pooled reduce + FC
    k_reduce<<<64, 128, 0, stream>>>(partial, pooled, nagg);
    k_final<<<1, 64, 0, stream>>>(pooled, Wfcf, bfcf, &cnts[0], SX, d_out, n);
}

// Round 7
// 348.320 us; speedup vs baseline: 1.4636x; 1.1198x over previous
//
#include <hip/hip_runtime.h>
#include <stdint.h>

#define FEAT 128

typedef short bf16x8 __attribute__((ext_vector_type(8)));
typedef unsigned short u16x8 __attribute__((ext_vector_type(8)));
typedef float f32x4 __attribute__((ext_vector_type(4)));

__device__ __forceinline__ float bflo(uint32_t u) {
    uint32_t t = u << 16;
    return __builtin_bit_cast(float, t);
}
__device__ __forceinline__ float bfhi(uint32_t u) {
    uint32_t t = u & 0xffff0000u;
    return __builtin_bit_cast(float, t);
}
__device__ __forceinline__ float bfs(unsigned short u) {
    uint32_t t = ((uint32_t)u) << 16;
    return __builtin_bit_cast(float, t);
}
__device__ __forceinline__ unsigned short f2bf(float f) {
    uint32_t u = __builtin_bit_cast(uint32_t, f);
    u += 0x7fffu + ((u >> 16) & 1u);
    return (unsigned short)(u >> 16);
}

// ---- dtype detection (one block per tensor) -----------------------------
__global__ void k_dtype5(const uint32_t* p0, const uint32_t* p1, const uint32_t* p2,
                         const uint32_t* p3, const uint32_t* p4,
                         int w0, int w1, int w2, int w3, int w4,
                         int* __restrict__ cnts) {
    const uint32_t* p; int words;
    switch (blockIdx.x) {
        case 0: p = p0; words = w0; break;
        case 1: p = p1; words = w1; break;
        case 2: p = p2; words = w2; break;
        case 3: p = p3; words = w3; break;
        default: p = p4; words = w4; break;
    }
    int t = threadIdx.x;
    int h = 0;
    for (int i = t; i < words; i += 256) {
        unsigned e = (p[i] >> 7) & 0xFFu;
        h += (e >= 0x60u && e <= 0x90u) ? 1 : 0;
    }
    atomicAdd(&cnts[blockIdx.x], h);
}

// ---- edge-index layout detection (int64 vs int32) -----------------------
__global__ void k_detect(const int* __restrict__ ei, int* __restrict__ flag) {
    int t = threadIdx.x;
    int nz = 0;
    for (int i = 0; i < 8; i++) {
        int w = 1 + 2 * (t * 8 + i);
        nz |= ei[w];
    }
    if (nz != 0) atomicOr(flag, 1);    // 1 => int32 layout, 0 => int64
}

// ---- edge decode: int64/int32 -> clamped int32 SoA ----------------------
__global__ void k_econv(const int* __restrict__ ei, const int* __restrict__ flag,
                        int* __restrict__ dstA, int* __restrict__ srcA,
                        int E, int n) {
    int e = blockIdx.x * 256 + threadIdx.x;
    if (e >= E) return;
    int is32 = *flag;
    int s = is32 ? ei[e]     : ei[2 * e];
    int d = is32 ? ei[E + e] : ei[2 * E + 2 * e];
    if ((unsigned)s >= (unsigned)n) s = 0;
    if ((unsigned)d >= (unsigned)n) d = 0;
    srcA[e] = s;
    dstA[e] = d;
}

// ---- input canonicalization ---------------------------------------------

__global__ void k_split(const void* __restrict__ in, const int* __restrict__ cnt,
                        int samples, int m8,
                        u16x8* __restrict__ hi, u16x8* __restrict__ lo) {
    int i = blockIdx.x * 256 + threadIdx.x;
    if (i >= m8) return;
    if (2 * (*cnt) > samples) {
        hi[i] = ((const u16x8*)in)[i];
        u16x8 z = {0,0,0,0,0,0,0,0};
        lo[i] = z;
    } else {
        const float4* f4 = (const float4*)in;
        float4 f0 = f4[2 * i], f1 = f4[2 * i + 1];
        float v[8] = {f0.x, f0.y, f0.z, f0.w, f1.x, f1.y, f1.z, f1.w};
        u16x8 h, l;
        #pragma unroll
        for (int j = 0; j < 8; j++) {
            unsigned short hh = f2bf(v[j]);
            h[j] = hh;
            l[j] = f2bf(v[j] - bfs(hh));
        }
        hi[i] = h;
        lo[i] = l;
    }
}

__global__ void k_wsplit(const void* __restrict__ W, const int* __restrict__ cnt,
                         int samples,
                         unsigned short* __restrict__ Wth, unsigned short* __restrict__ Wtl) {
    int t = blockIdx.x * 256 + threadIdx.x;  // 16384
    int nn = t >> 7, k = t & 127;
    int si = k * 128 + nn;
    float f;
    if (2 * (*cnt) > samples) f = bfs(((const unsigned short*)W)[si]);
    else                      f = ((const float*)W)[si];
    unsigned short h = f2bf(f);
    Wth[nn * 128 + k] = h;
    Wtl[nn * 128 + k] = f2bf(f - bfs(h));
}

// merged small-tensor convert: [b1|b2|Wfc|bfc] -> f32
__global__ void k_prep(const void* b1, const void* b2, const void* Wfc, const void* bfc,
                       const int* __restrict__ cnt, int samples,
                       float* b1f, float* b2f, float* Wfcf, float* bfcf) {
    int i = blockIdx.x * 256 + threadIdx.x;   // 0..4383
    if (i >= 4384) return;
    int isbf = (2 * (*cnt) > samples) ? 1 : 0;
    const void* src; float* dst; int off;
    if (i < 128)       { src = b1;  dst = b1f;  off = i; }
    else if (i < 256)  { src = b2;  dst = b2f;  off = i - 128; }
    else if (i < 4352) { src = Wfc; dst = Wfcf; off = i - 256; }
    else               { src = bfc; dst = bfcf; off = i - 4352; }
    dst[off] = isbf ? bfs(((const unsigned short*)src)[off])
                    : ((const float*)src)[off];
}

// ---- CSR build, XCD-partitioned -----------------------------------------

__global__ void k_degp(const int* __restrict__ dstA, int* __restrict__ deg,
                       int E, int psz) {
    int part  = blockIdx.x & 7;
    int chunk = blockIdx.x >> 3;
    int base  = chunk * 2048;
    int lo = part * psz, hi = lo + psz;
    #pragma unroll
    for (int j = 0; j < 8; j++) {
        int e = base + j * 256 + threadIdx.x;
        if (e < E) {
            int d = dstA[e];
            if (d >= lo && d < hi) atomicAdd(&deg[d], 1);
        }
    }
}

__global__ void k_scatp(const int* __restrict__ dstA, const int* __restrict__ srcA,
                        int* __restrict__ cursor, int* __restrict__ col,
                        int E, int psz) {
    int part  = blockIdx.x & 7;
    int chunk = blockIdx.x >> 3;
    int base  = chunk * 2048;
    int lo = part * psz, hi = lo + psz;
    #pragma unroll
    for (int j = 0; j < 8; j++) {
        int e = base + j * 256 + threadIdx.x;
        if (e < E) {
            int d = dstA[e];
            if (d >= lo && d < hi) {
                int p = atomicAdd(&cursor[d], 1);
                if ((unsigned)p < (unsigned)E) col[p] = srcA[e];
            }
        }
    }
}

// block sums (+ fused dinv)
__global__ void k_bsum(const int* __restrict__ deg, int* __restrict__ bsum,
                       float* __restrict__ dinv, int n) {
    __shared__ int ws[4];
    int t = threadIdx.x, lane = t & 63, w = t >> 6;
    int idx = blockIdx.x * 256 + t;
    int v = (idx < n) ? deg[idx] : 0;
    if (idx < n) dinv[idx] = rsqrtf((float)(v + 1));  // +1 self-loop
    int r = v;
    #pragma unroll
    for (int off = 32; off > 0; off >>= 1) r += __shfl_down(r, off, 64);
    if (lane == 0) ws[w] = r;
    __syncthreads();
    if (t == 0) bsum[blockIdx.x] = ws[0] + ws[1] + ws[2] + ws[3];
}

__global__ void k_bscan(const int* __restrict__ bsum, int* __restrict__ boff,
                        int* __restrict__ row_ptr, int nb, int n) {
    __shared__ int wsum[4];
    int t = threadIdx.x, lane = t & 63, w = t >> 6;
    int v = (t < nb) ? bsum[t] : 0;
    int s = v;
    #pragma unroll
    for (int off = 1; off < 64; off <<= 1) {
        int x = __shfl_up(s, off, 64);
        if (lane >= off) s += x;
    }
    if (lane == 63) wsum[w] = s;
    __syncthreads();
    if (t == 0) {
        int acc = 0;
        #pragma unroll
        for (int i = 0; i < 4; i++) { int x = wsum[i]; wsum[i] = acc; acc += x; }
    }
    __syncthreads();
    int excl = s - v + wsum[w];
    if (t < nb) boff[t] = excl;
    if (t == nb - 1) row_ptr[n] = excl + v;
}

__global__ void k_bapply(const int* __restrict__ deg, const int* __restrict__ boff,
                         int* __restrict__ row_ptr, int* __restrict__ cursor, int n) {
    __shared__ int wsum[4];
    int t = threadIdx.x, lane = t & 63, w = t >> 6;
    int idx = blockIdx.x * 256 + t;
    int v = (idx < n) ? deg[idx] : 0;
    int s = v;
    #pragma unroll
    for (int off = 1; off < 64; off <<= 1) {
        int x = __shfl_up(s, off, 64);
        if (lane >= off) s += x;
    }
    if (lane == 63) wsum[w] = s;
    __syncthreads();
    if (t == 0) {
        int acc = 0;
        #pragma unroll
        for (int i = 0; i < 4; i++) { int x = wsum[i]; wsum[i] = acc; acc += x; }
    }
    __syncthreads();
    int ex = boff[blockIdx.x] + s - v + wsum[w];
    if (idx < n) {
        row_ptr[idx] = ex;
        cursor[idx]  = ex;
    }
}

// ---- GEMM: hs_bf16 = dinv[row] * (X @ W), split-bf16 MFMA, bf16 out -----

__launch_bounds__(64)
__global__ void k_gemm(const unsigned short* __restrict__ Xh,
                       const unsigned short* __restrict__ Xl,
                       const unsigned short* __restrict__ Wth,
                       const unsigned short* __restrict__ Wtl,
                       const float* __restrict__ dinv,
                       unsigned short* __restrict__ hs, int n, int use_xlo) {
    int l = threadIdx.x;
    int quad = l >> 4;
    int m16 = l & 15;
    int r0 = blockIdx.x * 16;

    int ra = r0 + m16;
    if (ra > n - 1) ra = n - 1;
    const int4* Xvh = (const int4*)Xh;
    const int4* Xvl = (const int4*)Xl;
    bf16x8 ah[4], al[4];
    #pragma unroll
    for (int kt = 0; kt < 4; kt++)
        ah[kt] = __builtin_bit_cast(bf16x8, Xvh[ra * 16 + kt * 4 + quad]);
    if (use_xlo) {
        #pragma unroll
        for (int kt = 0; kt < 4; kt++)
            al[kt] = __builtin_bit_cast(bf16x8, Xvl[ra * 16 + kt * 4 + quad]);
    }

    float dv[4];
    #pragma unroll
    for (int reg = 0; reg < 4; reg++) {
        int row = r0 + quad * 4 + reg;
        if (row > n - 1) row = n - 1;
        dv[reg] = dinv[row];
    }

    const int4* Wvh = (const int4*)Wth;
    const int4* Wvl = (const int4*)Wtl;
    #pragma unroll
    for (int nt = 0; nt < 8; nt++) {
        f32x4 acc = {0.f, 0.f, 0.f, 0.f};
        int brow = (nt * 16 + m16) * 16;
        #pragma unroll
        for (int kt = 0; kt < 4; kt++) {
            bf16x8 bh = __builtin_bit_cast(bf16x8, Wvh[brow + kt * 4 + quad]);
            bf16x8 bl = __builtin_bit_cast(bf16x8, Wvl[brow + kt * 4 + quad]);
            acc = __builtin_amdgcn_mfma_f32_16x16x32_bf16(ah[kt], bh, acc, 0, 0, 0);
            acc = __builtin_amdgcn_mfma_f32_16x16x32_bf16(ah[kt], bl, acc, 0, 0, 0);
            if (use_xlo)
                acc = __builtin_amdgcn_mfma_f32_16x16x32_bf16(al[kt], bh, acc, 0, 0, 0);
        }
        #pragma unroll
        for (int reg = 0; reg < 4; reg++) {
            int row = r0 + quad * 4 + reg;
            if (row < n)
                hs[row * 128 + nt * 16 + m16] = f2bf(acc[reg] * dv[reg]);
        }
    }
}

// ---- Pull aggregation: act = relu(dinv*(hs[d]+sum hs[s]) + b) -----------

__launch_bounds__(256)
__global__ void k_agg(const uint32_t* __restrict__ hsv, const int* __restrict__ row_ptr,
                      const int* __restrict__ col, const float* __restrict__ dinv,
                      const float* __restrict__ bias,
                      uint32_t* __restrict__ outh, float* __restrict__ partial,
                      int n, int E) {
    __shared__ float pl[4][128];
    int wave = threadIdx.x >> 6;
    int lane = threadIdx.x & 63;
    int node = blockIdx.x * 4 + wave;
    bool active = (node < n);
    int nd = active ? node : 0;

    uint32_t su = hsv[nd * 64 + lane];   // self term (pre-scaled by dinv[node])
    float a0 = bflo(su), a1 = bfhi(su);

    int e = row_ptr[nd];
    int end = active ? row_ptr[nd + 1] : e;
    if (e < 0) e = 0;
    if (end > E) end = E;

    for (; e + 8 <= end; e += 8) {
        unsigned s0 = (unsigned)col[e],     s1 = (unsigned)col[e + 1];
        unsigned s2 = (unsigned)col[e + 2], s3 = (unsigned)col[e + 3];
        unsigned s4 = (unsigned)col[e + 4], s5 = (unsigned)col[e + 5];
        unsigned s6 = (unsigned)col[e + 6], s7 = (unsigned)col[e + 7];
        if (s0 >= (unsigned)n) s0 = 0;
        if (s1 >= (unsigned)n) s1 = 0;
        if (s2 >= (unsigned)n) s2 = 0;
        if (s3 >= (unsigned)n) s3 = 0;
        if (s4 >= (unsigned)n) s4 = 0;
        if (s5 >= (unsigned)n) s5 = 0;
        if (s6 >= (unsigned)n) s6 = 0;
        if (s7 >= (unsigned)n) s7 = 0;
        uint32_t u0 = hsv[s0 * 64 + lane];
        uint32_t u1 = hsv[s1 * 64 + lane];
        uint32_t u2 = hsv[s2 * 64 + lane];
        uint32_t u3 = hsv[s3 * 64 + lane];
        uint32_t u4 = hsv[s4 * 64 + lane];
        uint32_t u5 = hsv[s5 * 64 + lane];
        uint32_t u6 = hsv[s6 * 64 + lane];
        uint32_t u7 = hsv[s7 * 64 + lane];
        a0 += bflo(u0) + bflo(u1) + bflo(u2) + bflo(u3)
            + bflo(u4) + bflo(u5) + bflo(u6) + bflo(u7);
        a1 += bfhi(u0) + bfhi(u1) + bfhi(u2) + bfhi(u3)
            + bfhi(u4) + bfhi(u5) + bfhi(u6) + bfhi(u7);
    }
    for (; e < end; ++e) {
        unsigned s0 = (unsigned)col[e];
        if (s0 >= (unsigned)n) s0 = 0;
        uint32_t u = hsv[s0 * 64 + lane];
        a0 += bflo(u);
        a1 += bfhi(u);
    }

    float dv = dinv[nd];
    float2 bu = ((const float2*)bias)[lane];
    float r0 = fmaxf(dv * a0 + bu.x, 0.f);
    float r1 = fmaxf(dv * a1 + bu.y, 0.f);
    if (!active) { r0 = 0.f; r1 = 0.f; }

    if (outh != nullptr && active) {
        outh[node * 64 + lane] = (uint32_t)f2bf(r0) | ((uint32_t)f2bf(r1) << 16);
    }
    if (partial != nullptr) {
        pl[wave][2 * lane]     = r0;
        pl[wave][2 * lane + 1] = r1;
        __syncthreads();
        int t = threadIdx.x;
        if (t < 128) {
            float ps = pl[0][t] + pl[1][t] + pl[2][t] + pl[3][t];
            partial[blockIdx.x * 128 + t] = ps;
        }
    }
}

// ---- parallel pooled reduce: partial[nb][128] -> pooled[128] ------------
// 100 blocks x 256 threads; block owns contiguous row chunk; float4 flat
// reads (stride 1024 floats == 0 mod 128 -> thread's features invariant).

__launch_bounds__(256)
__global__ void k_red(const float* __restrict__ partial, float* __restrict__ pooled,
                      int nb) {
    __shared__ float red[8][128];
    int t = threadIdx.x;
    int chunk = (nb + gridDim.x - 1) / gridDim.x;
    int r0 = blockIdx.x * chunk;
    int r1 = r0 + chunk;
    if (r1 > nb) r1 = nb;

    float4 acc = {0.f, 0.f, 0.f, 0.f};
    const float4* p4 = (const float4*)partial;
    for (int i = r0 * 32 + t; i < r1 * 32; i += 256) {
        float4 v = p4[i];
        acc.x += v.x; acc.y += v.y; acc.z += v.z; acc.w += v.w;
    }
    int g = t >> 5;           // 0..7
    int fb = (t & 31) * 4;    // feature base 0..124
    red[g][fb]     = acc.x;
    red[g][fb + 1] = acc.y;
    red[g][fb + 2] = acc.z;
    red[g][fb + 3] = acc.w;
    __syncthreads();
    if (t < 128) {
        float s = red[0][t] + red[1][t] + red[2][t] + red[3][t]
                + red[4][t] + red[5][t] + red[6][t] + red[7][t];
        atomicAdd(&pooled[t], s);
    }
}

__global__ void k_final(const float* __restrict__ pooled,
                        const float* __restrict__ Wfcf,
                        const float* __restrict__ bfcf,
                        const int* __restrict__ xcnt, int xsamp,
                        void* __restrict__ out, int n) {
    int j = threadIdx.x;
    if (j >= 32) return;
    float s = 0.f;
    for (int c = 0; c < 128; ++c) s += pooled[c] * Wfcf[c * 32 + j];
    s = s * (1.0f / (float)n) + bfcf[j];
    if (2 * (*xcnt) > xsamp) ((unsigned short*)out)[j] = f2bf(s);
    else                     ((float*)out)[j] = s;
}

// ---- Launch -------------------------------------------------------------

extern "C" void kernel_launch(void* const* d_in, const int* in_sizes, int n_in,
                              void* d_out, int out_size, void* d_ws, size_t ws_size,
                              hipStream_t stream) {
    const void* x   = d_in[0];
    const int*  ei  = (const int*)d_in[1];
    const void* W1  = d_in[2];
    const void* b1  = d_in[3];
    const void* W2  = d_in[4];
    const void* b2  = d_in[5];
    const void* Wfc = d_in[6];
    const void* bfc = d_in[7];

    const int n = in_sizes[0] / FEAT;    // 50000
    const int E = in_sizes[1] / 2;       // 800000
    const int m = n * FEAT;              // 6.4M
    const int nb256 = (n + 255) / 256;   // 196
    const int nagg  = (n + 3) / 4;       // 12500
    const int psz   = (n + 7) / 8;       // dst-partition size (8 XCDs)
    const int nchunks = (E + 2047) / 2048;

    char* ws = (char*)d_ws;
    unsigned short* hs      = (unsigned short*)(ws);               // 12,800,000 bf16 hs
    unsigned short* xh      = (unsigned short*)(ws + 12800000);    // 12,800,000 (x hi / act1)
    unsigned short* xl      = (unsigned short*)(ws + 25600000);    // 12,800,000 (x lo / L2 partials)
    int*            col     = (int*)(ws + 38400000);               // 3,200,000
    int*            dstA    = (int*)(ws + 41600000);               // 3,200,000
    int*            srcA    = (int*)(ws + 44800000);               // 3,200,000
    int*            deg     = (int*)(ws + 48000000);               // 200,000
    int*            row_ptr = (int*)(ws + 48200000);               // 200,016
    int*            cursor  = (int*)(ws + 48400016);               // 200,000
    float*          dinv    = (float*)(ws + 48600016);             // 200,000
    unsigned short* Wth     = (unsigned short*)(ws + 48800016);    // 32,768
    unsigned short* Wtl     = (unsigned short*)(ws + 48832784);    // 32,768
    float*          b1f     = (float*)(ws + 48865552);             // 512
    float*          b2f     = (float*)(ws + 48866064);             // 512
    float*          Wfcf    = (float*)(ws + 48866576);             // 16,384
    float*          bfcf    = (float*)(ws + 48882960);             // 128
    float*          pooled  = (float*)(ws + 48883088);             // 512
    int*            eflag   = (int*)(ws + 48883600);               // 4
    int*            cnts    = (int*)(ws + 48883604);               // 20
    int*            bsum    = (int*)(ws + 48883624);               // 1,024
    int*            boff    = (int*)(ws + 48884648);               // 1,024

    if (ws_size < 48885672) return;  // diagnostic: zero output => ws too small

    hipMemsetAsync(deg, 0, (size_t)n * 4, stream);
    hipMemsetAsync(pooled, 0, 128 * 4, stream);
    hipMemsetAsync(eflag, 0, 24, stream);  // eflag + 5 cnts

    // dtype + edge-layout detection
    const int SX = 2048, SW = 2048, SWFC = 1024, SBFC = 16;
    k_dtype5<<<5, 256, 0, stream>>>((const uint32_t*)x, (const uint32_t*)W1,
                                    (const uint32_t*)W2, (const uint32_t*)Wfc,
                                    (const uint32_t*)bfc,
                                    SX, SW, SW, SWFC, SBFC, cnts);
    k_detect<<<1, 256, 0, stream>>>(ei, eflag);

    // CSR build (XCD-partitioned deg/scatter)
    k_econv<<<(E + 255) / 256, 256, 0, stream>>>(ei, eflag, dstA, srcA, E, n);
    k_degp<<<nchunks * 8, 256, 0, stream>>>(dstA, deg, E, psz);
    k_bsum<<<nb256, 256, 0, stream>>>(deg, bsum, dinv, n);
    k_bscan<<<1, 256, 0, stream>>>(bsum, boff, row_ptr, nb256, n);
    k_bapply<<<nb256, 256, 0, stream>>>(deg, boff, row_ptr, cursor, n);
    k_scatp<<<nchunks * 8, 256, 0, stream>>>(dstA, srcA, cursor, col, E, psz);

    // canonicalize inputs
    k_prep<<<18, 256, 0, stream>>>(b1, b2, Wfc, bfc, &cnts[3], SWFC,
                                   b1f, b2f, Wfcf, bfcf);
    k_split<<<(m / 8 + 255) / 256, 256, 0, stream>>>(x, &cnts[0], SX, m / 8,
                                                     (u16x8*)xh, (u16x8*)xl);

    int gemm_grid = (n + 15) / 16;

    // layer 1: act1 -> xh (plain bf16, overwrites x hi after its last use)
    k_wsplit<<<64, 256, 0, stream>>>(W1, &cnts[1], SW, Wth, Wtl);
    k_gemm<<<gemm_grid, 64, 0, stream>>>(xh, xl, Wth, Wtl, dinv, hs, n, 1);
    k_agg<<<nagg, 256, 0, stream>>>((const uint32_t*)hs, row_ptr, col, dinv, b1f,
                                    (uint32_t*)xh, nullptr, n, E);
    // layer 2: act never materialized; pooled partials into xl region
    float* partial = (float*)xl;
    k_wsplit<<<64, 256, 0, stream>>>(W2, &cnts[2], SW, Wth, Wtl);
    k_gemm<<<gemm_grid, 64, 0, stream>>>(xh, nullptr, Wth, Wtl, dinv, hs, n, 0);
    k_agg<<<nagg, 256, 0, stream>>>((const uint32_t*)hs, row_ptr, col, dinv, b2f,
                                    nullptr, partial, n, E);

    // pooled reduce + FC
    k_red<<<100, 256, 0, stream>>>(partial, pooled, nagg);
    k_final<<<1, 64, 0, stream>>>(pooled, Wfcf, bfcf, &cnts[0], SX, d_out, n);
}